// Round 1
// baseline (1037.797 us; speedup 1.0000x reference)
//
#include <hip/hip_runtime.h>
#include <hip/hip_bf16.h>

#define EPSV 1e-5f

// ---------------- block-wide sum (256 threads = 4 waves) ----------------
__device__ inline float block_sum(float v, float* lds) {
  #pragma unroll
  for (int o = 32; o; o >>= 1) v += __shfl_xor(v, o);
  int tid = threadIdx.x;
  if ((tid & 63) == 0) lds[tid >> 6] = v;
  __syncthreads();
  float r = lds[0] + lds[1] + lds[2] + lds[3];
  __syncthreads();
  return r;
}

__device__ inline float siluf(float x) { return x / (1.f + expf(-x)); }

// ---------------- LayerNorm over rows of length 128 ----------------
__global__ __launch_bounds__(256) void ln_rows128(const float* __restrict__ x,
                                                  const float* __restrict__ w,
                                                  const float* __restrict__ bb,
                                                  float* __restrict__ out) {
  long row = blockIdx.x;
  int tid = threadIdx.x;
  __shared__ float lds[4];
  const float* xr = x + row * 128;
  float v = (tid < 128) ? xr[tid] : 0.f;
  float m = block_sum(v, lds) * (1.f / 128.f);
  float d = (tid < 128) ? (v - m) : 0.f;
  float var = block_sum(d * d, lds) * (1.f / 128.f);
  float inv = rsqrtf(var + EPSV);
  if (tid < 128) out[row * 128 + tid] = (v - m) * inv * w[tid] + bb[tid];
}

// ------- LayerNorm over L=1024 of transposed x_spa: row r=(b, ch) -------
__global__ __launch_bounds__(256) void ln_spe_t(const float* __restrict__ xspa,
                                                const float* __restrict__ w,
                                                const float* __restrict__ bb,
                                                float* __restrict__ out) {
  int r = blockIdx.x;
  int b = r >> 7, ch = r & 127;
  int tid = threadIdx.x;
  __shared__ float lds[4];
  float xr[4];
  float s = 0.f;
  #pragma unroll
  for (int j = 0; j < 4; j++) {
    int l = tid + (j << 8);
    xr[j] = xspa[((long)b * 1024 + l) * 128 + ch];
    s += xr[j];
  }
  float m = block_sum(s, lds) * (1.f / 1024.f);
  float s2 = 0.f;
  #pragma unroll
  for (int j = 0; j < 4; j++) { float d = xr[j] - m; s2 += d * d; }
  float var = block_sum(s2, lds) * (1.f / 1024.f);
  float inv = rsqrtf(var + EPSV);
  #pragma unroll
  for (int j = 0; j < 4; j++) {
    int l = tid + (j << 8);
    out[(long)r * 1024 + l] = (xr[j] - m) * inv * w[l] + bb[l];
  }
}

// ---------------- fp32 GEMM: out[M,N] = A[M,K] @ W[K,N] ----------------
// MODE 0: plain. MODE 1: += R (same layout). MODE 2: transposed add:
//   r=(b,ch) with b=r>>7, ch=r&127; out[b][c][ch] = acc + R[b][c][ch]
template <int MODE>
__global__ __launch_bounds__(256) void gemm64(const float* __restrict__ A,
                                              const float* __restrict__ W,
                                              const float* __restrict__ R,
                                              float* __restrict__ out,
                                              int M, int N, int K) {
  __shared__ float As[16][65];
  __shared__ float Ws[16][64];
  int tid = threadIdx.x;
  int tx = tid & 15, ty = tid >> 4;
  int rowBase = blockIdx.y * 64, colBase = blockIdx.x * 64;
  float acc[4][4] = {};
  for (int k0 = 0; k0 < K; k0 += 16) {
    {
      int q = tid * 4;
      int m = q >> 4, kk = q & 15;
      const float4 av =
          *reinterpret_cast<const float4*>(A + (long)(rowBase + m) * K + k0 + kk);
      As[kk + 0][m] = av.x;
      As[kk + 1][m] = av.y;
      As[kk + 2][m] = av.z;
      As[kk + 3][m] = av.w;
    }
    {
      int q = tid * 4;
      int kk = q >> 6, n = q & 63;
      int col = colBase + n;
      float4 wv = make_float4(0.f, 0.f, 0.f, 0.f);
      if (col < N)
        wv = *reinterpret_cast<const float4*>(W + (long)(k0 + kk) * N + col);
      *reinterpret_cast<float4*>(&Ws[kk][n]) = wv;
    }
    __syncthreads();
    #pragma unroll
    for (int k = 0; k < 16; k++) {
      float a[4], w[4];
      #pragma unroll
      for (int i = 0; i < 4; i++) a[i] = As[k][ty * 4 + i];
      #pragma unroll
      for (int j = 0; j < 4; j++) w[j] = Ws[k][tx * 4 + j];
      #pragma unroll
      for (int i = 0; i < 4; i++)
        #pragma unroll
        for (int j = 0; j < 4; j++) acc[i][j] += a[i] * w[j];
    }
    __syncthreads();
  }
  #pragma unroll
  for (int i = 0; i < 4; i++) {
    int r = rowBase + ty * 4 + i;
    #pragma unroll
    for (int j = 0; j < 4; j++) {
      int c = colBase + tx * 4 + j;
      if (c < N) {
        float v = acc[i][j];
        if (MODE == 0) {
          out[(long)r * N + c] = v;
        } else if (MODE == 1) {
          out[(long)r * N + c] = v + R[(long)r * N + c];
        } else {
          int b = r >> 7, ch = r & 127;
          out[(long)b * 131072 + (long)c * 128 + ch] =
              v + R[((long)b * 1024 + c) * 128 + ch];
        }
      }
    }
  }
}

// ------------- causal depthwise conv (D_CONV=4) + bias + SiLU -------------
__global__ __launch_bounds__(256) void conv_silu(const float* __restrict__ zx,
                                                 const float* __restrict__ cw,
                                                 const float* __restrict__ cb,
                                                 float* __restrict__ out,
                                                 int Bb, int L, int conv_dim,
                                                 int ld, int col0) {
  long idx = (long)blockIdx.x * 256 + threadIdx.x;
  long total = (long)Bb * L * conv_dim;
  if (idx >= total) return;
  int ch = (int)(idx % conv_dim);
  long rt = idx / conv_dim;
  int t = (int)(rt % L);
  int b = (int)(rt / L);
  float acc = cb[ch];
  #pragma unroll
  for (int k = 0; k < 4; k++) {
    int tt = t + k - 3;
    if (tt >= 0)
      acc += cw[k * conv_dim + ch] * zx[((long)b * L + tt) * ld + col0 + ch];
  }
  out[idx] = siluf(acc);
}

// ---------------- dt = softplus(raw + bias); da = exp(dt*A) ----------------
__global__ __launch_bounds__(256) void dtda_kernel(const float* __restrict__ zx,
                                                   const float* __restrict__ dtb,
                                                   const float* __restrict__ alog,
                                                   float* __restrict__ dt,
                                                   float* __restrict__ da,
                                                   int rows, int H, int ld,
                                                   int col0) {
  int idx = blockIdx.x * 256 + threadIdx.x;
  if (idx >= rows * H) return;
  int h = idx % H;
  long row = idx / H;
  float v = zx[row * ld + col0 + h] + dtb[h];
  float sp = (v > 20.f) ? v : log1pf(expf(v));
  dt[idx] = sp;
  da[idx] = expf(-expf(alog[h]) * sp);
}

// ------------------------- sequential SSM scan -------------------------
// one block = one (b,h); 256 threads: p = tid&63, n-chunk = (tid>>6)*16
__global__ __launch_bounds__(256) void scan_kernel(const float* __restrict__ xbc,
                                                   const float* __restrict__ dt,
                                                   const float* __restrict__ da,
                                                   const float* __restrict__ Dvec,
                                                   float* __restrict__ y,
                                                   int L, int H, int conv_dim,
                                                   int d_inner) {
  int b = blockIdx.x / H, h = blockIdx.x % H;
  int tid = threadIdx.x, p = tid & 63, nc = tid >> 6, n0 = nc << 4;
  __shared__ float Bs[64], Cs[64], part[4][64];
  float hst[16];
  #pragma unroll
  for (int i = 0; i < 16; i++) hst[i] = 0.f;
  float Dv = Dvec[h];
  long row0 = (long)b * L;
  // preload t = 0
  float bld = 0.f, cld = 0.f;
  {
    const float* xr = xbc + row0 * conv_dim;
    if (tid < 64) bld = xr[d_inner + tid];
    else if (tid < 128) cld = xr[d_inner + tid];
  }
  float xh = xbc[row0 * conv_dim + (h << 6) + p];
  float dtv = dt[row0 * H + h];
  float dav = da[row0 * H + h];
  for (int t = 0; t < L; ++t) {
    if (tid < 64) Bs[tid] = bld;
    else if (tid < 128) Cs[tid - 64] = cld;
    __syncthreads();
    // prefetch t+1 while computing t
    float nb = 0.f, ncl = 0.f, nxh = 0.f, ndt = 0.f, nda = 0.f;
    if (t + 1 < L) {
      const float* xr2 = xbc + (row0 + t + 1) * conv_dim;
      if (tid < 64) nb = xr2[d_inner + tid];
      else if (tid < 128) ncl = xr2[d_inner + tid];
      nxh = xr2[(h << 6) + p];
      ndt = dt[(row0 + t + 1) * H + h];
      nda = da[(row0 + t + 1) * H + h];
    }
    float dtx = dtv * xh;
    float yp0 = 0.f, yp1 = 0.f;
    #pragma unroll
    for (int i = 0; i < 16; i += 2) {
      hst[i] = dav * hst[i] + dtx * Bs[n0 + i];
      yp0 += hst[i] * Cs[n0 + i];
      hst[i + 1] = dav * hst[i + 1] + dtx * Bs[n0 + i + 1];
      yp1 += hst[i + 1] * Cs[n0 + i + 1];
    }
    part[nc][p] = yp0 + yp1;
    __syncthreads();
    if (tid < 64) {
      y[(row0 + t) * d_inner + (h << 6) + tid] =
          part[0][tid] + part[1][tid] + part[2][tid] + part[3][tid] + Dv * xh;
    }
    bld = nb; cld = ncl; xh = nxh; dtv = ndt; dav = nda;
  }
}

// --------- g = y*silu(z); g *= rsqrt(mean(g^2)+eps)*rms_w (in place) ---------
template <int NJ>
__global__ __launch_bounds__(256) void gate_rms(float* __restrict__ y,
                                                const float* __restrict__ zx,
                                                const float* __restrict__ rmsw,
                                                int d_inner, int ld) {
  long row = blockIdx.x;
  float* yr = y + row * d_inner;
  const float* zr = zx + row * ld;
  __shared__ float lds[4];
  float g[NJ];
  float ss = 0.f;
  #pragma unroll
  for (int j = 0; j < NJ; j++) {
    int c = threadIdx.x + (j << 8);
    float gv = yr[c] * siluf(zr[c]);
    g[j] = gv;
    ss += gv * gv;
  }
  float tot = block_sum(ss, lds);
  float inv = rsqrtf(tot / (float)d_inner + EPSV);
  #pragma unroll
  for (int j = 0; j < NJ; j++) {
    int c = threadIdx.x + (j << 8);
    yr[c] = g[j] * inv * rmsw[c];
  }
}

extern "C" void kernel_launch(void* const* d_in, const int* in_sizes, int n_in,
                              void* d_out, int out_size, void* d_ws,
                              size_t ws_size, hipStream_t stream) {
  const float* x        = (const float*)d_in[0];
  const float* ln_spa_w = (const float*)d_in[1];
  const float* ln_spa_b = (const float*)d_in[2];
  const float* ln_spe_w = (const float*)d_in[3];
  const float* ln_spe_b = (const float*)d_in[4];
  const float* spa_W_in   = (const float*)d_in[5];
  const float* spa_conv_w = (const float*)d_in[6];
  const float* spa_conv_b = (const float*)d_in[7];
  const float* spa_dt_b   = (const float*)d_in[8];
  const float* spa_A_log  = (const float*)d_in[9];
  const float* spa_D      = (const float*)d_in[10];
  const float* spa_rms_w  = (const float*)d_in[11];
  const float* spa_W_out  = (const float*)d_in[12];
  const float* spe_W_in   = (const float*)d_in[13];
  const float* spe_conv_w = (const float*)d_in[14];
  const float* spe_conv_b = (const float*)d_in[15];
  const float* spe_dt_b   = (const float*)d_in[16];
  const float* spe_A_log  = (const float*)d_in[17];
  const float* spe_D      = (const float*)d_in[18];
  const float* spe_rms_w  = (const float*)d_in[19];
  const float* spe_W_out  = (const float*)d_in[20];
  float* out = (float*)d_out;

  float* ws = (float*)d_ws;
  float* xspa = ws;                    // 1,048,576  (persists across phases)
  float* S = ws + 1048576;             // shared scratch region

  // ---------- spatial mamba (seq len 1024, d_model 128) ----------
  float* xn  = S;                      // 8192*128   = 1,048,576
  float* zx  = S + 1048576;            // 8192*644   = 5,275,648
  float* cv  = zx + 5275648;           // 8192*384   = 3,145,728
  float* dtb = cv + 3145728;           // 8192*4     = 32,768
  float* dab = dtb + 32768;            // 32,768
  float* yb  = dab + 32768;            // 8192*256   = 2,097,152

  hipLaunchKernelGGL(ln_rows128, dim3(8192), dim3(256), 0, stream,
                     x, ln_spa_w, ln_spa_b, xn);
  hipLaunchKernelGGL((gemm64<0>), dim3(11, 128), dim3(256), 0, stream,
                     xn, spa_W_in, nullptr, zx, 8192, 644, 128);
  hipLaunchKernelGGL(conv_silu, dim3((8 * 1024 * 384 + 255) / 256), dim3(256), 0,
                     stream, zx, spa_conv_w, spa_conv_b, cv, 8, 1024, 384, 644, 256);
  hipLaunchKernelGGL(dtda_kernel, dim3((8192 * 4 + 255) / 256), dim3(256), 0,
                     stream, zx, spa_dt_b, spa_A_log, dtb, dab, 8192, 4, 644, 640);
  hipLaunchKernelGGL(scan_kernel, dim3(32), dim3(256), 0, stream,
                     cv, dtb, dab, spa_D, yb, 1024, 4, 384, 256);
  hipLaunchKernelGGL((gate_rms<1>), dim3(8192), dim3(256), 0, stream,
                     yb, zx, spa_rms_w, 256, 644);
  hipLaunchKernelGGL((gemm64<1>), dim3(2, 128), dim3(256), 0, stream,
                     yb, spa_W_out, x, xspa, 8192, 128, 256);

  // ---------- spectral mamba (seq len 128, d_model 1024) ----------
  float* xn2  = S;                     // 1024*1024  = 1,048,576
  float* zx2  = S + 1048576;           // 1024*4256  = 4,358,144
  float* cv2  = zx2 + 4358144;         // 1024*2176  = 2,228,224
  float* dtb2 = cv2 + 2228224;         // 1024*32    = 32,768
  float* dab2 = dtb2 + 32768;          // 32,768
  float* yb2  = dab2 + 32768;          // 1024*2048  = 2,097,152

  hipLaunchKernelGGL(ln_spe_t, dim3(1024), dim3(256), 0, stream,
                     xspa, ln_spe_w, ln_spe_b, xn2);
  hipLaunchKernelGGL((gemm64<0>), dim3(67, 16), dim3(256), 0, stream,
                     xn2, spe_W_in, nullptr, zx2, 1024, 4256, 1024);
  hipLaunchKernelGGL(conv_silu, dim3((8 * 128 * 2176 + 255) / 256), dim3(256), 0,
                     stream, zx2, spe_conv_w, spe_conv_b, cv2, 8, 128, 2176, 4256, 2048);
  hipLaunchKernelGGL(dtda_kernel, dim3((1024 * 32 + 255) / 256), dim3(256), 0,
                     stream, zx2, spe_dt_b, spe_A_log, dtb2, dab2, 1024, 32, 4256, 4224);
  hipLaunchKernelGGL(scan_kernel, dim3(256), dim3(256), 0, stream,
                     cv2, dtb2, dab2, spe_D, yb2, 128, 32, 2176, 2048);
  hipLaunchKernelGGL((gate_rms<8>), dim3(1024), dim3(256), 0, stream,
                     yb2, zx2, spe_rms_w, 2048, 4256);
  hipLaunchKernelGGL((gemm64<2>), dim3(16, 16), dim3(256), 0, stream,
                     yb2, spe_W_out, xspa, out, 1024, 1024, 2048);
}

// Round 2
// 679.995 us; speedup vs baseline: 1.5262x; 1.5262x over previous
//
#include <hip/hip_runtime.h>
#include <hip/hip_bf16.h>

#define EPSV 1e-5f

// ---------------- block-wide sum (256 threads = 4 waves) ----------------
__device__ inline float block_sum(float v, float* lds) {
  #pragma unroll
  for (int o = 32; o; o >>= 1) v += __shfl_xor(v, o);
  int tid = threadIdx.x;
  if ((tid & 63) == 0) lds[tid >> 6] = v;
  __syncthreads();
  float r = lds[0] + lds[1] + lds[2] + lds[3];
  __syncthreads();
  return r;
}

__device__ inline float siluf(float x) { return x / (1.f + expf(-x)); }

// ---------------- LayerNorm over rows of length 128 ----------------
__global__ __launch_bounds__(256) void ln_rows128(const float* __restrict__ x,
                                                  const float* __restrict__ w,
                                                  const float* __restrict__ bb,
                                                  float* __restrict__ out) {
  long row = blockIdx.x;
  int tid = threadIdx.x;
  __shared__ float lds[4];
  const float* xr = x + row * 128;
  float v = (tid < 128) ? xr[tid] : 0.f;
  float m = block_sum(v, lds) * (1.f / 128.f);
  float d = (tid < 128) ? (v - m) : 0.f;
  float var = block_sum(d * d, lds) * (1.f / 128.f);
  float inv = rsqrtf(var + EPSV);
  if (tid < 128) out[row * 128 + tid] = (v - m) * inv * w[tid] + bb[tid];
}

// ------- LayerNorm over L=1024 of transposed x_spa: row r=(b, ch) -------
__global__ __launch_bounds__(256) void ln_spe_t(const float* __restrict__ xspa,
                                                const float* __restrict__ w,
                                                const float* __restrict__ bb,
                                                float* __restrict__ out) {
  int r = blockIdx.x;
  int b = r >> 7, ch = r & 127;
  int tid = threadIdx.x;
  __shared__ float lds[4];
  float xr[4];
  float s = 0.f;
  #pragma unroll
  for (int j = 0; j < 4; j++) {
    int l = tid + (j << 8);
    xr[j] = xspa[((long)b * 1024 + l) * 128 + ch];
    s += xr[j];
  }
  float m = block_sum(s, lds) * (1.f / 1024.f);
  float s2 = 0.f;
  #pragma unroll
  for (int j = 0; j < 4; j++) { float d = xr[j] - m; s2 += d * d; }
  float var = block_sum(s2, lds) * (1.f / 1024.f);
  float inv = rsqrtf(var + EPSV);
  #pragma unroll
  for (int j = 0; j < 4; j++) {
    int l = tid + (j << 8);
    out[(long)r * 1024 + l] = (xr[j] - m) * inv * w[l] + bb[l];
  }
}

// ---------------- fp32 GEMM: out[M,N] = A[M,K] @ W[K,N] ----------------
// MODE 0: plain. MODE 1: += R (same layout). MODE 2: transposed add:
//   r=(b,ch) with b=r>>7, ch=r&127; out[b][c][ch] = acc + R[b][c][ch]
template <int MODE>
__global__ __launch_bounds__(256) void gemm64(const float* __restrict__ A,
                                              const float* __restrict__ W,
                                              const float* __restrict__ R,
                                              float* __restrict__ out,
                                              int M, int N, int K) {
  __shared__ float As[16][65];
  __shared__ float Ws[16][64];
  int tid = threadIdx.x;
  int tx = tid & 15, ty = tid >> 4;
  int rowBase = blockIdx.y * 64, colBase = blockIdx.x * 64;
  float acc[4][4] = {};
  for (int k0 = 0; k0 < K; k0 += 16) {
    {
      int q = tid * 4;
      int m = q >> 4, kk = q & 15;
      const float4 av =
          *reinterpret_cast<const float4*>(A + (long)(rowBase + m) * K + k0 + kk);
      As[kk + 0][m] = av.x;
      As[kk + 1][m] = av.y;
      As[kk + 2][m] = av.z;
      As[kk + 3][m] = av.w;
    }
    {
      int q = tid * 4;
      int kk = q >> 6, n = q & 63;
      int col = colBase + n;
      float4 wv = make_float4(0.f, 0.f, 0.f, 0.f);
      if (col < N)
        wv = *reinterpret_cast<const float4*>(W + (long)(k0 + kk) * N + col);
      *reinterpret_cast<float4*>(&Ws[kk][n]) = wv;
    }
    __syncthreads();
    #pragma unroll
    for (int k = 0; k < 16; k++) {
      float a[4], w[4];
      #pragma unroll
      for (int i = 0; i < 4; i++) a[i] = As[k][ty * 4 + i];
      #pragma unroll
      for (int j = 0; j < 4; j++) w[j] = Ws[k][tx * 4 + j];
      #pragma unroll
      for (int i = 0; i < 4; i++)
        #pragma unroll
        for (int j = 0; j < 4; j++) acc[i][j] += a[i] * w[j];
    }
    __syncthreads();
  }
  #pragma unroll
  for (int i = 0; i < 4; i++) {
    int r = rowBase + ty * 4 + i;
    #pragma unroll
    for (int j = 0; j < 4; j++) {
      int c = colBase + tx * 4 + j;
      if (c < N) {
        float v = acc[i][j];
        if (MODE == 0) {
          out[(long)r * N + c] = v;
        } else if (MODE == 1) {
          out[(long)r * N + c] = v + R[(long)r * N + c];
        } else {
          int b = r >> 7, ch = r & 127;
          out[(long)b * 131072 + (long)c * 128 + ch] =
              v + R[((long)b * 1024 + c) * 128 + ch];
        }
      }
    }
  }
}

// ------------- causal depthwise conv (D_CONV=4) + bias + SiLU -------------
__global__ __launch_bounds__(256) void conv_silu(const float* __restrict__ zx,
                                                 const float* __restrict__ cw,
                                                 const float* __restrict__ cb,
                                                 float* __restrict__ out,
                                                 int Bb, int L, int conv_dim,
                                                 int ld, int col0) {
  long idx = (long)blockIdx.x * 256 + threadIdx.x;
  long total = (long)Bb * L * conv_dim;
  if (idx >= total) return;
  int ch = (int)(idx % conv_dim);
  long rt = idx / conv_dim;
  int t = (int)(rt % L);
  int b = (int)(rt / L);
  float acc = cb[ch];
  #pragma unroll
  for (int k = 0; k < 4; k++) {
    int tt = t + k - 3;
    if (tt >= 0)
      acc += cw[k * conv_dim + ch] * zx[((long)b * L + tt) * ld + col0 + ch];
  }
  out[idx] = siluf(acc);
}

// ---------------- dt = softplus(raw + bias); da = exp(dt*A) ----------------
__global__ __launch_bounds__(256) void dtda_kernel(const float* __restrict__ zx,
                                                   const float* __restrict__ dtb,
                                                   const float* __restrict__ alog,
                                                   float* __restrict__ dt,
                                                   float* __restrict__ da,
                                                   int rows, int H, int ld,
                                                   int col0) {
  int idx = blockIdx.x * 256 + threadIdx.x;
  if (idx >= rows * H) return;
  int h = idx % H;
  long row = idx / H;
  float v = zx[row * ld + col0 + h] + dtb[h];
  float sp = (v > 20.f) ? v : log1pf(expf(v));
  dt[idx] = sp;
  da[idx] = expf(-expf(alog[h]) * sp);
}

// ------------------------- staged sequential SSM scan -------------------------
// one block = one (b,h); 256 threads: p = tid>>2 (0..63), nc = tid&3, n0 = nc*16.
// Chunks of SCAN_T timesteps staged in double-buffered LDS; global loads for
// chunk c+1 issued before computing chunk c (async-STAGE split), ds_write after.
#define SCAN_T 16
__global__ __launch_bounds__(256) void scan_staged(const float* __restrict__ xbc,
                                                   const float* __restrict__ dt,
                                                   const float* __restrict__ da,
                                                   const float* __restrict__ Dvec,
                                                   float* __restrict__ y,
                                                   int L, int H, int conv_dim,
                                                   int d_inner) {
  int b = blockIdx.x / H, h = blockIdx.x % H;
  int tid = threadIdx.x;
  int p = tid >> 2, nc = tid & 3, n0 = nc << 4;
  __shared__ float Xs[2][SCAN_T][64];     // x head slice
  __shared__ float BCs[2][SCAN_T][128];   // B (0..63) | C (64..127)
  __shared__ float Ds[2][SCAN_T][2];      // dt, da
  float hst[16];
  #pragma unroll
  for (int i = 0; i < 16; i++) hst[i] = 0.f;
  float Dv = Dvec[h];
  long row0 = (long)b * L;
  int nchunks = L / SCAN_T;

  // staging index decomposition (fixed per thread)
  const int xs_s = tid >> 4, xs_o = (tid & 15) << 2;   // X: 16 float4/step
  const int bc_s = tid >> 5, bc_o = (tid & 31) << 2;   // BC: 32 float4/step, 2 passes
  float4 xr, bc0, bc1;
  float dval = 0.f;

  // prologue: stage chunk 0
  {
    long t0 = row0;
    xr  = *reinterpret_cast<const float4*>(xbc + (t0 + xs_s) * conv_dim + (h << 6) + xs_o);
    bc0 = *reinterpret_cast<const float4*>(xbc + (t0 + bc_s) * conv_dim + d_inner + bc_o);
    bc1 = *reinterpret_cast<const float4*>(xbc + (t0 + 8 + bc_s) * conv_dim + d_inner + bc_o);
    if (tid < 32) {
      const float* src = (tid & 1) ? da : dt;
      dval = src[(t0 + (tid >> 1)) * H + h];
    }
    *reinterpret_cast<float4*>(&Xs[0][xs_s][xs_o]) = xr;
    *reinterpret_cast<float4*>(&BCs[0][bc_s][bc_o]) = bc0;
    *reinterpret_cast<float4*>(&BCs[0][8 + bc_s][bc_o]) = bc1;
    if (tid < 32) Ds[0][tid >> 1][tid & 1] = dval;
  }
  __syncthreads();

  for (int c = 0; c < nchunks; ++c) {
    int buf = c & 1;
    // issue next-chunk global loads (latency hides under the 16-step compute)
    if (c + 1 < nchunks) {
      long t0 = row0 + (long)(c + 1) * SCAN_T;
      xr  = *reinterpret_cast<const float4*>(xbc + (t0 + xs_s) * conv_dim + (h << 6) + xs_o);
      bc0 = *reinterpret_cast<const float4*>(xbc + (t0 + bc_s) * conv_dim + d_inner + bc_o);
      bc1 = *reinterpret_cast<const float4*>(xbc + (t0 + 8 + bc_s) * conv_dim + d_inner + bc_o);
      if (tid < 32) {
        const float* src = (tid & 1) ? da : dt;
        dval = src[(t0 + (tid >> 1)) * H + h];
      }
    }
    #pragma unroll
    for (int t = 0; t < SCAN_T; ++t) {
      float dtv = Ds[buf][t][0];
      float dav = Ds[buf][t][1];
      float xh = Xs[buf][t][p];
      float dtx = dtv * xh;
      const float* Bp = &BCs[buf][t][n0];
      const float* Cp = &BCs[buf][t][64 + n0];
      float yv = 0.f;
      #pragma unroll
      for (int i = 0; i < 16; i++) {
        hst[i] = dav * hst[i] + dtx * Bp[i];
        yv += hst[i] * Cp[i];
      }
      yv += __shfl_xor(yv, 1);
      yv += __shfl_xor(yv, 2);
      if (nc == 0)
        y[(row0 + (long)c * SCAN_T + t) * d_inner + (h << 6) + p] = yv + Dv * xh;
    }
    __syncthreads();  // all waves done reading buf
    if (c + 1 < nchunks) {
      *reinterpret_cast<float4*>(&Xs[buf ^ 1][xs_s][xs_o]) = xr;
      *reinterpret_cast<float4*>(&BCs[buf ^ 1][bc_s][bc_o]) = bc0;
      *reinterpret_cast<float4*>(&BCs[buf ^ 1][8 + bc_s][bc_o]) = bc1;
      if (tid < 32) Ds[buf ^ 1][tid >> 1][tid & 1] = dval;
      __syncthreads();  // staged data visible before next chunk's compute
    }
  }
}

// --------- g = y*silu(z); g *= rsqrt(mean(g^2)+eps)*rms_w (in place) ---------
template <int NJ>
__global__ __launch_bounds__(256) void gate_rms(float* __restrict__ y,
                                                const float* __restrict__ zx,
                                                const float* __restrict__ rmsw,
                                                int d_inner, int ld) {
  long row = blockIdx.x;
  float* yr = y + row * d_inner;
  const float* zr = zx + row * ld;
  __shared__ float lds[4];
  float g[NJ];
  float ss = 0.f;
  #pragma unroll
  for (int j = 0; j < NJ; j++) {
    int c = threadIdx.x + (j << 8);
    float gv = yr[c] * siluf(zr[c]);
    g[j] = gv;
    ss += gv * gv;
  }
  float tot = block_sum(ss, lds);
  float inv = rsqrtf(tot / (float)d_inner + EPSV);
  #pragma unroll
  for (int j = 0; j < NJ; j++) {
    int c = threadIdx.x + (j << 8);
    yr[c] = g[j] * inv * rmsw[c];
  }
}

extern "C" void kernel_launch(void* const* d_in, const int* in_sizes, int n_in,
                              void* d_out, int out_size, void* d_ws,
                              size_t ws_size, hipStream_t stream) {
  const float* x        = (const float*)d_in[0];
  const float* ln_spa_w = (const float*)d_in[1];
  const float* ln_spa_b = (const float*)d_in[2];
  const float* ln_spe_w = (const float*)d_in[3];
  const float* ln_spe_b = (const float*)d_in[4];
  const float* spa_W_in   = (const float*)d_in[5];
  const float* spa_conv_w = (const float*)d_in[6];
  const float* spa_conv_b = (const float*)d_in[7];
  const float* spa_dt_b   = (const float*)d_in[8];
  const float* spa_A_log  = (const float*)d_in[9];
  const float* spa_D      = (const float*)d_in[10];
  const float* spa_rms_w  = (const float*)d_in[11];
  const float* spa_W_out  = (const float*)d_in[12];
  const float* spe_W_in   = (const float*)d_in[13];
  const float* spe_conv_w = (const float*)d_in[14];
  const float* spe_conv_b = (const float*)d_in[15];
  const float* spe_dt_b   = (const float*)d_in[16];
  const float* spe_A_log  = (const float*)d_in[17];
  const float* spe_D      = (const float*)d_in[18];
  const float* spe_rms_w  = (const float*)d_in[19];
  const float* spe_W_out  = (const float*)d_in[20];
  float* out = (float*)d_out;

  float* ws = (float*)d_ws;
  float* xspa = ws;                    // 1,048,576  (persists across phases)
  float* S = ws + 1048576;             // shared scratch region

  // ---------- spatial mamba (seq len 1024, d_model 128) ----------
  float* xn  = S;                      // 8192*128   = 1,048,576
  float* zx  = S + 1048576;            // 8192*644   = 5,275,648
  float* cv  = zx + 5275648;           // 8192*384   = 3,145,728
  float* dtb = cv + 3145728;           // 8192*4     = 32,768
  float* dab = dtb + 32768;            // 32,768
  float* yb  = dab + 32768;            // 8192*256   = 2,097,152

  hipLaunchKernelGGL(ln_rows128, dim3(8192), dim3(256), 0, stream,
                     x, ln_spa_w, ln_spa_b, xn);
  hipLaunchKernelGGL((gemm64<0>), dim3(11, 128), dim3(256), 0, stream,
                     xn, spa_W_in, nullptr, zx, 8192, 644, 128);
  hipLaunchKernelGGL(conv_silu, dim3((8 * 1024 * 384 + 255) / 256), dim3(256), 0,
                     stream, zx, spa_conv_w, spa_conv_b, cv, 8, 1024, 384, 644, 256);
  hipLaunchKernelGGL(dtda_kernel, dim3((8192 * 4 + 255) / 256), dim3(256), 0,
                     stream, zx, spa_dt_b, spa_A_log, dtb, dab, 8192, 4, 644, 640);
  hipLaunchKernelGGL(scan_staged, dim3(32), dim3(256), 0, stream,
                     cv, dtb, dab, spa_D, yb, 1024, 4, 384, 256);
  hipLaunchKernelGGL((gate_rms<1>), dim3(8192), dim3(256), 0, stream,
                     yb, zx, spa_rms_w, 256, 644);
  hipLaunchKernelGGL((gemm64<1>), dim3(2, 128), dim3(256), 0, stream,
                     yb, spa_W_out, x, xspa, 8192, 128, 256);

  // ---------- spectral mamba (seq len 128, d_model 1024) ----------
  float* xn2  = S;                     // 1024*1024  = 1,048,576
  float* zx2  = S + 1048576;           // 1024*4256  = 4,358,144
  float* cv2  = zx2 + 4358144;         // 1024*2176  = 2,228,224
  float* dtb2 = cv2 + 2228224;         // 1024*32    = 32,768
  float* dab2 = dtb2 + 32768;          // 32,768
  float* yb2  = dab2 + 32768;          // 1024*2048  = 2,097,152

  hipLaunchKernelGGL(ln_spe_t, dim3(1024), dim3(256), 0, stream,
                     xspa, ln_spe_w, ln_spe_b, xn2);
  hipLaunchKernelGGL((gemm64<0>), dim3(67, 16), dim3(256), 0, stream,
                     xn2, spe_W_in, nullptr, zx2, 1024, 4256, 1024);
  hipLaunchKernelGGL(conv_silu, dim3((8 * 128 * 2176 + 255) / 256), dim3(256), 0,
                     stream, zx2, spe_conv_w, spe_conv_b, cv2, 8, 128, 2176, 4256, 2048);
  hipLaunchKernelGGL(dtda_kernel, dim3((1024 * 32 + 255) / 256), dim3(256), 0,
                     stream, zx2, spe_dt_b, spe_A_log, dtb2, dab2, 1024, 32, 4256, 4224);
  hipLaunchKernelGGL(scan_staged, dim3(256), dim3(256), 0, stream,
                     cv2, dtb2, dab2, spe_D, yb2, 128, 32, 2176, 2048);
  hipLaunchKernelGGL((gate_rms<8>), dim3(1024), dim3(256), 0, stream,
                     yb2, zx2, spe_rms_w, 2048, 4256);
  hipLaunchKernelGGL((gemm64<2>), dim3(16, 16), dim3(256), 0, stream,
                     yb2, spe_W_out, xspa, out, 1024, 1024, 2048);
}

// Round 3
// 449.638 us; speedup vs baseline: 2.3081x; 1.5123x over previous
//
#include <hip/hip_runtime.h>
#include <hip/hip_bf16.h>

#define EPSV 1e-5f

typedef __attribute__((ext_vector_type(8))) short short8v;   // 8 bf16 in 4 VGPRs
typedef __attribute__((ext_vector_type(4))) float f32x4;

__device__ inline unsigned short f2bf(float f) {
  __hip_bfloat16 h = __float2bfloat16(f);
  return *reinterpret_cast<unsigned short*>(&h);
}

// ---------------- block-wide sum (256 threads = 4 waves) ----------------
__device__ inline float block_sum(float v, float* lds) {
  #pragma unroll
  for (int o = 32; o; o >>= 1) v += __shfl_xor(v, o);
  int tid = threadIdx.x;
  if ((tid & 63) == 0) lds[tid >> 6] = v;
  __syncthreads();
  float r = lds[0] + lds[1] + lds[2] + lds[3];
  __syncthreads();
  return r;
}

__device__ inline float siluf(float x) { return x / (1.f + expf(-x)); }

// ---------------- LayerNorm over rows of length 128 ----------------
__global__ __launch_bounds__(256) void ln_rows128(const float* __restrict__ x,
                                                  const float* __restrict__ w,
                                                  const float* __restrict__ bb,
                                                  float* __restrict__ out) {
  long row = blockIdx.x;
  int tid = threadIdx.x;
  __shared__ float lds[4];
  const float* xr = x + row * 128;
  float v = (tid < 128) ? xr[tid] : 0.f;
  float m = block_sum(v, lds) * (1.f / 128.f);
  float d = (tid < 128) ? (v - m) : 0.f;
  float var = block_sum(d * d, lds) * (1.f / 128.f);
  float inv = rsqrtf(var + EPSV);
  if (tid < 128) out[row * 128 + tid] = (v - m) * inv * w[tid] + bb[tid];
}

// ------- LayerNorm over L=1024 of transposed x_spa: row r=(b, ch) -------
__global__ __launch_bounds__(256) void ln_spe_t(const float* __restrict__ xspa,
                                                const float* __restrict__ w,
                                                const float* __restrict__ bb,
                                                float* __restrict__ out) {
  int r = blockIdx.x;
  int b = r >> 7, ch = r & 127;
  int tid = threadIdx.x;
  __shared__ float lds[4];
  float xr[4];
  float s = 0.f;
  #pragma unroll
  for (int j = 0; j < 4; j++) {
    int l = tid + (j << 8);
    xr[j] = xspa[((long)b * 1024 + l) * 128 + ch];
    s += xr[j];
  }
  float m = block_sum(s, lds) * (1.f / 1024.f);
  float s2 = 0.f;
  #pragma unroll
  for (int j = 0; j < 4; j++) { float d = xr[j] - m; s2 += d * d; }
  float var = block_sum(s2, lds) * (1.f / 1024.f);
  float inv = rsqrtf(var + EPSV);
  #pragma unroll
  for (int j = 0; j < 4; j++) {
    int l = tid + (j << 8);
    out[(long)r * 1024 + l] = (xr[j] - m) * inv * w[l] + bb[l];
  }
}

// ---------------- fp32 GEMM (spa phase): out[M,N] = A[M,K] @ W[K,N] ----------------
// MODE 0: plain. MODE 1: += R (same layout).
template <int MODE>
__global__ __launch_bounds__(256) void gemm64(const float* __restrict__ A,
                                              const float* __restrict__ W,
                                              const float* __restrict__ R,
                                              float* __restrict__ out,
                                              int M, int N, int K) {
  __shared__ float As[16][65];
  __shared__ float Ws[16][64];
  int tid = threadIdx.x;
  int tx = tid & 15, ty = tid >> 4;
  int rowBase = blockIdx.y * 64, colBase = blockIdx.x * 64;
  float acc[4][4] = {};
  for (int k0 = 0; k0 < K; k0 += 16) {
    {
      int q = tid * 4;
      int m = q >> 4, kk = q & 15;
      const float4 av =
          *reinterpret_cast<const float4*>(A + (long)(rowBase + m) * K + k0 + kk);
      As[kk + 0][m] = av.x;
      As[kk + 1][m] = av.y;
      As[kk + 2][m] = av.z;
      As[kk + 3][m] = av.w;
    }
    {
      int q = tid * 4;
      int kk = q >> 6, n = q & 63;
      int col = colBase + n;
      float4 wv = make_float4(0.f, 0.f, 0.f, 0.f);
      if (col < N)
        wv = *reinterpret_cast<const float4*>(W + (long)(k0 + kk) * N + col);
      *reinterpret_cast<float4*>(&Ws[kk][n]) = wv;
    }
    __syncthreads();
    #pragma unroll
    for (int k = 0; k < 16; k++) {
      float a[4], w[4];
      #pragma unroll
      for (int i = 0; i < 4; i++) a[i] = As[k][ty * 4 + i];
      #pragma unroll
      for (int j = 0; j < 4; j++) w[j] = Ws[k][tx * 4 + j];
      #pragma unroll
      for (int i = 0; i < 4; i++)
        #pragma unroll
        for (int j = 0; j < 4; j++) acc[i][j] += a[i] * w[j];
    }
    __syncthreads();
  }
  #pragma unroll
  for (int i = 0; i < 4; i++) {
    int r = rowBase + ty * 4 + i;
    #pragma unroll
    for (int j = 0; j < 4; j++) {
      int c = colBase + tx * 4 + j;
      if (c < N) {
        float v = acc[i][j];
        if (MODE == 0) out[(long)r * N + c] = v;
        else           out[(long)r * N + c] = v + R[(long)r * N + c];
      }
    }
  }
}

// ---------------- fp32 -> bf16 elementwise convert (float4 granularity) ----------------
__global__ __launch_bounds__(256) void f2bf4(const float* __restrict__ in,
                                             unsigned short* __restrict__ out,
                                             long n4) {
  long i = (long)blockIdx.x * 256 + threadIdx.x;
  if (i >= n4) return;
  float4 v = reinterpret_cast<const float4*>(in)[i];
  ushort4 o;
  o.x = f2bf(v.x); o.y = f2bf(v.y); o.z = f2bf(v.z); o.w = f2bf(v.w);
  reinterpret_cast<ushort4*>(out)[i] = o;
}

// ------- W[K][N] fp32 -> Wt[N][K] bf16 (LDS-tiled transpose-convert) -------
// grid: ((N+63)/64, K/64); K must be a multiple of 64, N a multiple of 4.
__global__ __launch_bounds__(256) void wtconv(const float* __restrict__ W,
                                              unsigned short* __restrict__ Wt,
                                              int K, int N) {
  __shared__ float tile[64][65];
  int n0 = blockIdx.x * 64, k0 = blockIdx.y * 64;
  int tid = threadIdx.x;
  int r = tid >> 4, c4 = (tid & 15) * 4;
  #pragma unroll
  for (int i = 0; i < 4; i++) {
    int kk = r + i * 16;
    float4 v = make_float4(0.f, 0.f, 0.f, 0.f);
    if (n0 + c4 < N) v = *reinterpret_cast<const float4*>(&W[(long)(k0 + kk) * N + n0 + c4]);
    tile[kk][c4] = v.x; tile[kk][c4 + 1] = v.y; tile[kk][c4 + 2] = v.z; tile[kk][c4 + 3] = v.w;
  }
  __syncthreads();
  #pragma unroll
  for (int i = 0; i < 4; i++) {
    int nl = r + i * 16;
    if (n0 + nl < N) {
      ushort4 o;
      o.x = f2bf(tile[c4 + 0][nl]);
      o.y = f2bf(tile[c4 + 1][nl]);
      o.z = f2bf(tile[c4 + 2][nl]);
      o.w = f2bf(tile[c4 + 3][nl]);
      *reinterpret_cast<ushort4*>(&Wt[(long)(n0 + nl) * K + k0 + c4]) = o;
    }
  }
}

// ---------------- bf16 MFMA GEMM: out[M,N] = A[M,K] @ Bt[N,K]^T ----------------
// A: bf16 [M][K] row-major; Bt: bf16 [N][K] (i.e. W transposed). fp32 out.
// MODE 0: plain. MODE 2: transposed add epilogue (spe W_out):
//   out[b][c][ch] = acc + R[b][c][ch] with r=(b,ch): b=r>>7, ch=r&127.
// M % 64 == 0, K % 32 == 0 required; N guarded.
template <int MODE>
__global__ __launch_bounds__(256) void gemm_mfma(const unsigned short* __restrict__ A,
                                                 const unsigned short* __restrict__ Bt,
                                                 const float* __restrict__ R,
                                                 float* __restrict__ out,
                                                 int M, int N, int K) {
  __shared__ unsigned short As[64 * 40];   // rows padded 32->40 bf16
  __shared__ unsigned short Bs[64 * 40];
  int tid = threadIdx.x;
  int lane = tid & 63, w = tid >> 6;
  int wr = (w >> 1) * 32, wc = (w & 1) * 32;
  int ln15 = lane & 15, kg = lane >> 4;
  int rowBase = blockIdx.y * 64, colBase = blockIdx.x * 64;
  int sm = tid >> 2, skb = (tid & 3) * 8;
  f32x4 acc[2][2] = {};
  for (int k0 = 0; k0 < K; k0 += 32) {
    {
      short8v av = *reinterpret_cast<const short8v*>(&A[(long)(rowBase + sm) * K + k0 + skb]);
      *reinterpret_cast<short8v*>(&As[sm * 40 + skb]) = av;
      int n = colBase + sm;
      short8v bv = {0, 0, 0, 0, 0, 0, 0, 0};
      if (n < N) bv = *reinterpret_cast<const short8v*>(&Bt[(long)n * K + k0 + skb]);
      *reinterpret_cast<short8v*>(&Bs[sm * 40 + skb]) = bv;
    }
    __syncthreads();
    short8v af[2], bfr[2];
    #pragma unroll
    for (int mt = 0; mt < 2; mt++)
      af[mt] = *reinterpret_cast<const short8v*>(&As[(wr + mt * 16 + ln15) * 40 + kg * 8]);
    #pragma unroll
    for (int nt = 0; nt < 2; nt++)
      bfr[nt] = *reinterpret_cast<const short8v*>(&Bs[(wc + nt * 16 + ln15) * 40 + kg * 8]);
    #pragma unroll
    for (int mt = 0; mt < 2; mt++)
      #pragma unroll
      for (int nt = 0; nt < 2; nt++)
        acc[mt][nt] = __builtin_amdgcn_mfma_f32_16x16x32_bf16(af[mt], bfr[nt], acc[mt][nt], 0, 0, 0);
    __syncthreads();
  }
  #pragma unroll
  for (int mt = 0; mt < 2; mt++)
    #pragma unroll
    for (int nt = 0; nt < 2; nt++)
      #pragma unroll
      for (int q = 0; q < 4; q++) {
        int r = rowBase + wr + mt * 16 + kg * 4 + q;
        int c = colBase + wc + nt * 16 + ln15;
        if (c < N) {
          float v = acc[mt][nt][q];
          if (MODE == 0) {
            out[(long)r * N + c] = v;
          } else {
            int bb = r >> 7, ch = r & 127;
            out[(long)bb * 131072 + (long)c * 128 + ch] =
                v + R[((long)bb * 1024 + c) * 128 + ch];
          }
        }
      }
}

// ------------- causal depthwise conv (D_CONV=4) + bias + SiLU -------------
__global__ __launch_bounds__(256) void conv_silu(const float* __restrict__ zx,
                                                 const float* __restrict__ cw,
                                                 const float* __restrict__ cb,
                                                 float* __restrict__ out,
                                                 int Bb, int L, int conv_dim,
                                                 int ld, int col0) {
  long idx = (long)blockIdx.x * 256 + threadIdx.x;
  long total = (long)Bb * L * conv_dim;
  if (idx >= total) return;
  int ch = (int)(idx % conv_dim);
  long rt = idx / conv_dim;
  int t = (int)(rt % L);
  int b = (int)(rt / L);
  float acc = cb[ch];
  #pragma unroll
  for (int k = 0; k < 4; k++) {
    int tt = t + k - 3;
    if (tt >= 0)
      acc += cw[k * conv_dim + ch] * zx[((long)b * L + tt) * ld + col0 + ch];
  }
  out[idx] = siluf(acc);
}

// ---------------- dt = softplus(raw + bias); da = exp(dt*A) ----------------
__global__ __launch_bounds__(256) void dtda_kernel(const float* __restrict__ zx,
                                                   const float* __restrict__ dtb,
                                                   const float* __restrict__ alog,
                                                   float* __restrict__ dt,
                                                   float* __restrict__ da,
                                                   int rows, int H, int ld,
                                                   int col0) {
  int idx = blockIdx.x * 256 + threadIdx.x;
  if (idx >= rows * H) return;
  int h = idx % H;
  long row = idx / H;
  float v = zx[row * ld + col0 + h] + dtb[h];
  float sp = (v > 20.f) ? v : log1pf(expf(v));
  dt[idx] = sp;
  da[idx] = expf(-expf(alog[h]) * sp);
}

// ------------------------- staged sequential SSM scan v3 -------------------------
// G = threads per p (covers 64 n-states in G groups of NN=64/G).
// NSP = #blocks splitting the p dimension (p-rows are independent; outputs disjoint).
// Block owns PP=256/G p-values: p_global = ns*PP + tid/G. 16-step chunks,
// double-buffered LDS, next-chunk global loads issued before compute (T14).
template <int G, int NSP>
__global__ __launch_bounds__(256) void scan_v3(const float* __restrict__ xbc,
                                               const float* __restrict__ dt,
                                               const float* __restrict__ da,
                                               const float* __restrict__ Dvec,
                                               float* __restrict__ y,
                                               int L, int H, int conv_dim,
                                               int d_inner) {
  constexpr int PP = 256 / G;
  constexpr int NN = 64 / G;
  constexpr int NV = NN / 4;
  constexpr int XT = PP * 16 / 4;   // float4 loads per chunk for X
  int blk = blockIdx.x;
  int ns = blk % NSP;
  int bh = blk / NSP;
  int h = bh % H, b = bh / H;
  int tid = threadIdx.x;
  int nc = tid & (G - 1);
  int pl = tid / G;
  int n0 = nc * NN;
  __shared__ float Xs[2][16][PP];
  __shared__ float BCs[2][16][128];
  __shared__ float Ds[2][16][2];
  float hst[NN];
  #pragma unroll
  for (int i = 0; i < NN; i++) hst[i] = 0.f;
  float Dv = Dvec[h];
  long row0 = (long)b * L;
  int nchunks = L / 16;
  const int xs_s = tid / (PP / 4);
  const int xs_o = (tid % (PP / 4)) * 4;
  const int bc_s = tid >> 5, bc_o = (tid & 31) * 4;
  float4 xr = make_float4(0, 0, 0, 0), bc0 = xr, bc1 = xr;
  float dval = 0.f;

  auto issue = [&](long t0) {
    if (tid < XT)
      xr = *reinterpret_cast<const float4*>(
          &xbc[(t0 + xs_s) * conv_dim + (h << 6) + ns * PP + xs_o]);
    bc0 = *reinterpret_cast<const float4*>(&xbc[(t0 + bc_s) * conv_dim + d_inner + bc_o]);
    bc1 = *reinterpret_cast<const float4*>(&xbc[(t0 + 8 + bc_s) * conv_dim + d_inner + bc_o]);
    if (tid < 32) dval = ((tid & 1) ? da : dt)[(t0 + (tid >> 1)) * H + h];
  };
  auto commit = [&](int buf) {
    if (tid < XT) *reinterpret_cast<float4*>(&Xs[buf][xs_s][xs_o]) = xr;
    *reinterpret_cast<float4*>(&BCs[buf][bc_s][bc_o]) = bc0;
    *reinterpret_cast<float4*>(&BCs[buf][8 + bc_s][bc_o]) = bc1;
    if (tid < 32) Ds[buf][tid >> 1][tid & 1] = dval;
  };

  issue(row0);
  commit(0);
  __syncthreads();

  for (int c = 0; c < nchunks; ++c) {
    int buf = c & 1;
    if (c + 1 < nchunks) issue(row0 + (long)(c + 1) * 16);
    #pragma unroll
    for (int t = 0; t < 16; ++t) {
      float2 dd = *reinterpret_cast<const float2*>(&Ds[buf][t][0]);
      float xh = Xs[buf][t][pl];
      float dtx = dd.x * xh;
      float dav = dd.y;
      const float4* Bp = reinterpret_cast<const float4*>(&BCs[buf][t][n0]);
      const float4* Cp = reinterpret_cast<const float4*>(&BCs[buf][t][64 + n0]);
      float yv = 0.f;
      #pragma unroll
      for (int q = 0; q < NV; q++) {
        float4 bv = Bp[q], cv = Cp[q];
        hst[q * 4 + 0] = dav * hst[q * 4 + 0] + dtx * bv.x; yv += hst[q * 4 + 0] * cv.x;
        hst[q * 4 + 1] = dav * hst[q * 4 + 1] + dtx * bv.y; yv += hst[q * 4 + 1] * cv.y;
        hst[q * 4 + 2] = dav * hst[q * 4 + 2] + dtx * bv.z; yv += hst[q * 4 + 2] * cv.z;
        hst[q * 4 + 3] = dav * hst[q * 4 + 3] + dtx * bv.w; yv += hst[q * 4 + 3] * cv.w;
      }
      #pragma unroll
      for (int o = 1; o < G; o <<= 1) yv += __shfl_xor(yv, o);
      if (nc == 0)
        y[(row0 + c * 16 + t) * d_inner + (h << 6) + ns * PP + pl] = yv + Dv * xh;
    }
    __syncthreads();
    if (c + 1 < nchunks) {
      commit(buf ^ 1);
      __syncthreads();
    }
  }
}

// --------- g = y*silu(z); g *= rsqrt(mean(g^2)+eps)*rms_w (in place) ---------
template <int NJ>
__global__ __launch_bounds__(256) void gate_rms(float* __restrict__ y,
                                                const float* __restrict__ zx,
                                                const float* __restrict__ rmsw,
                                                int d_inner, int ld) {
  long row = blockIdx.x;
  float* yr = y + row * d_inner;
  const float* zr = zx + row * ld;
  __shared__ float lds[4];
  float g[NJ];
  float ss = 0.f;
  #pragma unroll
  for (int j = 0; j < NJ; j++) {
    int c = threadIdx.x + (j << 8);
    float gv = yr[c] * siluf(zr[c]);
    g[j] = gv;
    ss += gv * gv;
  }
  float tot = block_sum(ss, lds);
  float inv = rsqrtf(tot / (float)d_inner + EPSV);
  #pragma unroll
  for (int j = 0; j < NJ; j++) {
    int c = threadIdx.x + (j << 8);
    yr[c] = g[j] * inv * rmsw[c];
  }
}

extern "C" void kernel_launch(void* const* d_in, const int* in_sizes, int n_in,
                              void* d_out, int out_size, void* d_ws,
                              size_t ws_size, hipStream_t stream) {
  const float* x        = (const float*)d_in[0];
  const float* ln_spa_w = (const float*)d_in[1];
  const float* ln_spa_b = (const float*)d_in[2];
  const float* ln_spe_w = (const float*)d_in[3];
  const float* ln_spe_b = (const float*)d_in[4];
  const float* spa_W_in   = (const float*)d_in[5];
  const float* spa_conv_w = (const float*)d_in[6];
  const float* spa_conv_b = (const float*)d_in[7];
  const float* spa_dt_b   = (const float*)d_in[8];
  const float* spa_A_log  = (const float*)d_in[9];
  const float* spa_D      = (const float*)d_in[10];
  const float* spa_rms_w  = (const float*)d_in[11];
  const float* spa_W_out  = (const float*)d_in[12];
  const float* spe_W_in   = (const float*)d_in[13];
  const float* spe_conv_w = (const float*)d_in[14];
  const float* spe_conv_b = (const float*)d_in[15];
  const float* spe_dt_b   = (const float*)d_in[16];
  const float* spe_A_log  = (const float*)d_in[17];
  const float* spe_D      = (const float*)d_in[18];
  const float* spe_rms_w  = (const float*)d_in[19];
  const float* spe_W_out  = (const float*)d_in[20];
  float* out = (float*)d_out;

  float* ws = (float*)d_ws;
  float* xspa = ws;                    // 1,048,576 floats (persists across phases)
  float* S = ws + 1048576;             // shared scratch region

  // ---------- spatial mamba (seq len 1024, d_model 128) ----------
  float* xn  = S;                      // 1,048,576
  float* zx  = S + 1048576;            // 5,275,648
  float* cv  = zx + 5275648;           // 3,145,728
  float* dtb = cv + 3145728;           // 32,768
  float* dab = dtb + 32768;            // 32,768
  float* yb  = dab + 32768;            // 2,097,152

  hipLaunchKernelGGL(ln_rows128, dim3(8192), dim3(256), 0, stream,
                     x, ln_spa_w, ln_spa_b, xn);
  hipLaunchKernelGGL((gemm64<0>), dim3(11, 128), dim3(256), 0, stream,
                     xn, spa_W_in, nullptr, zx, 8192, 644, 128);
  hipLaunchKernelGGL(conv_silu, dim3((8 * 1024 * 384 + 255) / 256), dim3(256), 0,
                     stream, zx, spa_conv_w, spa_conv_b, cv, 8, 1024, 384, 644, 256);
  hipLaunchKernelGGL(dtda_kernel, dim3((8192 * 4 + 255) / 256), dim3(256), 0,
                     stream, zx, spa_dt_b, spa_A_log, dtb, dab, 8192, 4, 644, 640);
  // G=16 (4 n/thread), p split across 4 blocks: grid = 8*4*4 = 128
  hipLaunchKernelGGL((scan_v3<16, 4>), dim3(128), dim3(256), 0, stream,
                     cv, dtb, dab, spa_D, yb, 1024, 4, 384, 256);
  hipLaunchKernelGGL((gate_rms<1>), dim3(8192), dim3(256), 0, stream,
                     yb, zx, spa_rms_w, 256, 644);
  hipLaunchKernelGGL((gemm64<1>), dim3(2, 128), dim3(256), 0, stream,
                     yb, spa_W_out, x, xspa, 8192, 128, 256);

  // ---------- spectral mamba (seq len 128, d_model 1024) ----------
  float* xn2  = S;                     // 1,048,576
  float* zx2  = S + 1048576;           // 4,358,144
  float* cv2  = zx2 + 4358144;         // 2,228,224
  float* dtb2 = cv2 + 2228224;         // 32,768
  float* dab2 = dtb2 + 32768;          // 32,768
  float* yb2  = dab2 + 32768;          // 2,097,152

  hipLaunchKernelGGL(ln_spe_t, dim3(1024), dim3(256), 0, stream,
                     xspa, ln_spe_w, ln_spe_b, xn2);

  // -- spe W_in GEMM in bf16 MFMA; scratch overlays dead cv2..yb2 region --
  unsigned short* Abf   = (unsigned short*)cv2;            // 1024*1024 bf16
  unsigned short* Wt_in = (unsigned short*)(cv2 + 524288); // 4256*1024 bf16
  hipLaunchKernelGGL(f2bf4, dim3(1024), dim3(256), 0, stream,
                     xn2, Abf, (long)262144);
  hipLaunchKernelGGL(wtconv, dim3(67, 16), dim3(256), 0, stream,
                     spe_W_in, Wt_in, 1024, 4256);
  hipLaunchKernelGGL((gemm_mfma<0>), dim3(67, 16), dim3(256), 0, stream,
                     Abf, Wt_in, nullptr, zx2, 1024, 4256, 1024);

  hipLaunchKernelGGL(conv_silu, dim3((8 * 128 * 2176 + 255) / 256), dim3(256), 0,
                     stream, zx2, spe_conv_w, spe_conv_b, cv2, 8, 128, 2176, 4256, 2048);
  hipLaunchKernelGGL(dtda_kernel, dim3((1024 * 32 + 255) / 256), dim3(256), 0,
                     stream, zx2, spe_dt_b, spe_A_log, dtb2, dab2, 1024, 32, 4256, 4224);
  hipLaunchKernelGGL((scan_v3<4, 1>), dim3(256), dim3(256), 0, stream,
                     cv2, dtb2, dab2, spe_D, yb2, 128, 32, 2176, 2048);
  hipLaunchKernelGGL((gate_rms<8>), dim3(1024), dim3(256), 0, stream,
                     yb2, zx2, spe_rms_w, 2048, 4256);

  // -- spe W_out GEMM in bf16 MFMA; scratch fits inside dead cv2 --
  unsigned short* Abf2   = (unsigned short*)cv2;             // 1024*2048 bf16
  unsigned short* Wt_out = (unsigned short*)(cv2 + 1048576); // 1024*2048 bf16
  hipLaunchKernelGGL(f2bf4, dim3(2048), dim3(256), 0, stream,
                     yb2, Abf2, (long)524288);
  hipLaunchKernelGGL(wtconv, dim3(16, 32), dim3(256), 0, stream,
                     spe_W_out, Wt_out, 2048, 1024);
  hipLaunchKernelGGL((gemm_mfma<2>), dim3(16, 16), dim3(256), 0, stream,
                     Abf2, Wt_out, xspa, out, 1024, 1024, 2048);
}

// Round 4
// 350.238 us; speedup vs baseline: 2.9631x; 1.2838x over previous
//
#include <hip/hip_runtime.h>
#include <hip/hip_bf16.h>

#define EPSV 1e-5f

typedef __attribute__((ext_vector_type(8))) short short8v;   // 8 bf16 in 4 VGPRs
typedef __attribute__((ext_vector_type(4))) float f32x4;

__device__ inline unsigned short f2bf(float f) {
  __hip_bfloat16 h = __float2bfloat16(f);
  return *reinterpret_cast<unsigned short*>(&h);
}

// ---------------- block-wide sum (256 threads = 4 waves) ----------------
__device__ inline float block_sum(float v, float* lds) {
  #pragma unroll
  for (int o = 32; o; o >>= 1) v += __shfl_xor(v, o);
  int tid = threadIdx.x;
  if ((tid & 63) == 0) lds[tid >> 6] = v;
  __syncthreads();
  float r = lds[0] + lds[1] + lds[2] + lds[3];
  __syncthreads();
  return r;
}

__device__ inline float siluf(float x) { return x / (1.f + expf(-x)); }

// ---------------- LayerNorm over rows of length 128 ----------------
__global__ __launch_bounds__(256) void ln_rows128(const float* __restrict__ x,
                                                  const float* __restrict__ w,
                                                  const float* __restrict__ bb,
                                                  float* __restrict__ out) {
  long row = blockIdx.x;
  int tid = threadIdx.x;
  __shared__ float lds[4];
  const float* xr = x + row * 128;
  float v = (tid < 128) ? xr[tid] : 0.f;
  float m = block_sum(v, lds) * (1.f / 128.f);
  float d = (tid < 128) ? (v - m) : 0.f;
  float var = block_sum(d * d, lds) * (1.f / 128.f);
  float inv = rsqrtf(var + EPSV);
  if (tid < 128) out[row * 128 + tid] = (v - m) * inv * w[tid] + bb[tid];
}

// ------- LayerNorm over L=1024 of transposed x_spa: row r=(b, ch) -------
__global__ __launch_bounds__(256) void ln_spe_t(const float* __restrict__ xspa,
                                                const float* __restrict__ w,
                                                const float* __restrict__ bb,
                                                float* __restrict__ out) {
  int r = blockIdx.x;
  int b = r >> 7, ch = r & 127;
  int tid = threadIdx.x;
  __shared__ float lds[4];
  float xr[4];
  float s = 0.f;
  #pragma unroll
  for (int j = 0; j < 4; j++) {
    int l = tid + (j << 8);
    xr[j] = xspa[((long)b * 1024 + l) * 128 + ch];
    s += xr[j];
  }
  float m = block_sum(s, lds) * (1.f / 1024.f);
  float s2 = 0.f;
  #pragma unroll
  for (int j = 0; j < 4; j++) { float d = xr[j] - m; s2 += d * d; }
  float var = block_sum(s2, lds) * (1.f / 1024.f);
  float inv = rsqrtf(var + EPSV);
  #pragma unroll
  for (int j = 0; j < 4; j++) {
    int l = tid + (j << 8);
    out[(long)r * 1024 + l] = (xr[j] - m) * inv * w[l] + bb[l];
  }
}

// ---------------- fp32 GEMM (spa phase): out[M,N] = A[M,K] @ W[K,N] ----------------
// MODE 0: plain. MODE 1: += R (same layout).
template <int MODE>
__global__ __launch_bounds__(256) void gemm64(const float* __restrict__ A,
                                              const float* __restrict__ W,
                                              const float* __restrict__ R,
                                              float* __restrict__ out,
                                              int M, int N, int K) {
  __shared__ float As[16][65];
  __shared__ float Ws[16][64];
  int tid = threadIdx.x;
  int tx = tid & 15, ty = tid >> 4;
  int rowBase = blockIdx.y * 64, colBase = blockIdx.x * 64;
  float acc[4][4] = {};
  for (int k0 = 0; k0 < K; k0 += 16) {
    {
      int q = tid * 4;
      int m = q >> 4, kk = q & 15;
      const float4 av =
          *reinterpret_cast<const float4*>(A + (long)(rowBase + m) * K + k0 + kk);
      As[kk + 0][m] = av.x;
      As[kk + 1][m] = av.y;
      As[kk + 2][m] = av.z;
      As[kk + 3][m] = av.w;
    }
    {
      int q = tid * 4;
      int kk = q >> 6, n = q & 63;
      int col = colBase + n;
      float4 wv = make_float4(0.f, 0.f, 0.f, 0.f);
      if (col < N)
        wv = *reinterpret_cast<const float4*>(W + (long)(k0 + kk) * N + col);
      *reinterpret_cast<float4*>(&Ws[kk][n]) = wv;
    }
    __syncthreads();
    #pragma unroll
    for (int k = 0; k < 16; k++) {
      float a[4], w[4];
      #pragma unroll
      for (int i = 0; i < 4; i++) a[i] = As[k][ty * 4 + i];
      #pragma unroll
      for (int j = 0; j < 4; j++) w[j] = Ws[k][tx * 4 + j];
      #pragma unroll
      for (int i = 0; i < 4; i++)
        #pragma unroll
        for (int j = 0; j < 4; j++) acc[i][j] += a[i] * w[j];
    }
    __syncthreads();
  }
  #pragma unroll
  for (int i = 0; i < 4; i++) {
    int r = rowBase + ty * 4 + i;
    #pragma unroll
    for (int j = 0; j < 4; j++) {
      int c = colBase + tx * 4 + j;
      if (c < N) {
        float v = acc[i][j];
        if (MODE == 0) out[(long)r * N + c] = v;
        else           out[(long)r * N + c] = v + R[(long)r * N + c];
      }
    }
  }
}

// ---------------- fp32 -> bf16 elementwise convert (float4 granularity) ----------------
__global__ __launch_bounds__(256) void f2bf4(const float* __restrict__ in,
                                             unsigned short* __restrict__ out,
                                             long n4) {
  long i = (long)blockIdx.x * 256 + threadIdx.x;
  if (i >= n4) return;
  float4 v = reinterpret_cast<const float4*>(in)[i];
  ushort4 o;
  o.x = f2bf(v.x); o.y = f2bf(v.y); o.z = f2bf(v.z); o.w = f2bf(v.w);
  reinterpret_cast<ushort4*>(out)[i] = o;
}

// ------- W[K][N] fp32 -> Wt[N][K] bf16 (LDS-tiled transpose-convert) -------
// grid: ((N+63)/64, K/64); K must be a multiple of 64, N a multiple of 4.
__global__ __launch_bounds__(256) void wtconv(const float* __restrict__ W,
                                              unsigned short* __restrict__ Wt,
                                              int K, int N) {
  __shared__ float tile[64][65];
  int n0 = blockIdx.x * 64, k0 = blockIdx.y * 64;
  int tid = threadIdx.x;
  int r = tid >> 4, c4 = (tid & 15) * 4;
  #pragma unroll
  for (int i = 0; i < 4; i++) {
    int kk = r + i * 16;
    float4 v = make_float4(0.f, 0.f, 0.f, 0.f);
    if (n0 + c4 < N) v = *reinterpret_cast<const float4*>(&W[(long)(k0 + kk) * N + n0 + c4]);
    tile[kk][c4] = v.x; tile[kk][c4 + 1] = v.y; tile[kk][c4 + 2] = v.z; tile[kk][c4 + 3] = v.w;
  }
  __syncthreads();
  #pragma unroll
  for (int i = 0; i < 4; i++) {
    int nl = r + i * 16;
    if (n0 + nl < N) {
      ushort4 o;
      o.x = f2bf(tile[c4 + 0][nl]);
      o.y = f2bf(tile[c4 + 1][nl]);
      o.z = f2bf(tile[c4 + 2][nl]);
      o.w = f2bf(tile[c4 + 3][nl]);
      *reinterpret_cast<ushort4*>(&Wt[(long)(n0 + nl) * K + k0 + c4]) = o;
    }
  }
}

// ---------------- bf16 MFMA GEMM: out[M,N] = A[M,K] @ Bt[N,K]^T ----------------
// MODE 0: plain. MODE 2: transposed add epilogue (spe W_out).
template <int MODE>
__global__ __launch_bounds__(256) void gemm_mfma(const unsigned short* __restrict__ A,
                                                 const unsigned short* __restrict__ Bt,
                                                 const float* __restrict__ R,
                                                 float* __restrict__ out,
                                                 int M, int N, int K) {
  __shared__ unsigned short As[64 * 40];   // rows padded 32->40 bf16
  __shared__ unsigned short Bs[64 * 40];
  int tid = threadIdx.x;
  int lane = tid & 63, w = tid >> 6;
  int wr = (w >> 1) * 32, wc = (w & 1) * 32;
  int ln15 = lane & 15, kg = lane >> 4;
  int rowBase = blockIdx.y * 64, colBase = blockIdx.x * 64;
  int sm = tid >> 2, skb = (tid & 3) * 8;
  f32x4 acc[2][2] = {};
  for (int k0 = 0; k0 < K; k0 += 32) {
    {
      short8v av = *reinterpret_cast<const short8v*>(&A[(long)(rowBase + sm) * K + k0 + skb]);
      *reinterpret_cast<short8v*>(&As[sm * 40 + skb]) = av;
      int n = colBase + sm;
      short8v bv = {0, 0, 0, 0, 0, 0, 0, 0};
      if (n < N) bv = *reinterpret_cast<const short8v*>(&Bt[(long)n * K + k0 + skb]);
      *reinterpret_cast<short8v*>(&Bs[sm * 40 + skb]) = bv;
    }
    __syncthreads();
    short8v af[2], bfr[2];
    #pragma unroll
    for (int mt = 0; mt < 2; mt++)
      af[mt] = *reinterpret_cast<const short8v*>(&As[(wr + mt * 16 + ln15) * 40 + kg * 8]);
    #pragma unroll
    for (int nt = 0; nt < 2; nt++)
      bfr[nt] = *reinterpret_cast<const short8v*>(&Bs[(wc + nt * 16 + ln15) * 40 + kg * 8]);
    #pragma unroll
    for (int mt = 0; mt < 2; mt++)
      #pragma unroll
      for (int nt = 0; nt < 2; nt++)
        acc[mt][nt] = __builtin_amdgcn_mfma_f32_16x16x32_bf16(af[mt], bfr[nt], acc[mt][nt], 0, 0, 0);
    __syncthreads();
  }
  #pragma unroll
  for (int mt = 0; mt < 2; mt++)
    #pragma unroll
    for (int nt = 0; nt < 2; nt++)
      #pragma unroll
      for (int q = 0; q < 4; q++) {
        int r = rowBase + wr + mt * 16 + kg * 4 + q;
        int c = colBase + wc + nt * 16 + ln15;
        if (c < N) {
          float v = acc[mt][nt][q];
          if (MODE == 0) {
            out[(long)r * N + c] = v;
          } else {
            int bb = r >> 7, ch = r & 127;
            out[(long)bb * 131072 + (long)c * 128 + ch] =
                v + R[((long)bb * 1024 + c) * 128 + ch];
          }
        }
      }
}

// ------------- causal depthwise conv (D_CONV=4) + bias + SiLU -------------
__global__ __launch_bounds__(256) void conv_silu(const float* __restrict__ zx,
                                                 const float* __restrict__ cw,
                                                 const float* __restrict__ cb,
                                                 float* __restrict__ out,
                                                 int Bb, int L, int conv_dim,
                                                 int ld, int col0) {
  long idx = (long)blockIdx.x * 256 + threadIdx.x;
  long total = (long)Bb * L * conv_dim;
  if (idx >= total) return;
  int ch = (int)(idx % conv_dim);
  long rt = idx / conv_dim;
  int t = (int)(rt % L);
  int b = (int)(rt / L);
  float acc = cb[ch];
  #pragma unroll
  for (int k = 0; k < 4; k++) {
    int tt = t + k - 3;
    if (tt >= 0)
      acc += cw[k * conv_dim + ch] * zx[((long)b * L + tt) * ld + col0 + ch];
  }
  out[idx] = siluf(acc);
}

// ---------------- dt = softplus(raw + bias); da = exp(dt*A) ----------------
__global__ __launch_bounds__(256) void dtda_kernel(const float* __restrict__ zx,
                                                   const float* __restrict__ dtb,
                                                   const float* __restrict__ alog,
                                                   float* __restrict__ dt,
                                                   float* __restrict__ da,
                                                   int rows, int H, int ld,
                                                   int col0) {
  int idx = blockIdx.x * 256 + threadIdx.x;
  if (idx >= rows * H) return;
  int h = idx % H;
  long row = idx / H;
  float v = zx[row * ld + col0 + h] + dtb[h];
  float sp = (v > 20.f) ? v : log1pf(expf(v));
  dt[idx] = sp;
  da[idx] = expf(-expf(alog[h]) * sp);
}

// ------------------------- staged sequential SSM scan v4 -------------------------
// Like v3 but the cross-lane reduction is DEFERRED out of the 16-step loop:
// the loop body is pure {LDS reads + FMA} (so the compiler can pipeline DS ops
// with fine-grained lgkmcnt), and the 16 shuffle-reduction chains run after the
// loop as independent chains (latency overlapped by ILP).
template <int G, int NSP>
__global__ __launch_bounds__(256) void scan_v4(const float* __restrict__ xbc,
                                               const float* __restrict__ dt,
                                               const float* __restrict__ da,
                                               const float* __restrict__ Dvec,
                                               float* __restrict__ y,
                                               int L, int H, int conv_dim,
                                               int d_inner) {
  constexpr int PP = 256 / G;
  constexpr int NN = 64 / G;
  constexpr int NV = NN / 4;
  constexpr int XT = PP * 16 / 4;   // float4 loads per chunk for X
  int blk = blockIdx.x;
  int ns = blk % NSP;
  int bh = blk / NSP;
  int h = bh % H, b = bh / H;
  int tid = threadIdx.x;
  int nc = tid & (G - 1);
  int pl = tid / G;
  int n0 = nc * NN;
  __shared__ float Xs[2][16][PP];
  __shared__ float BCs[2][16][128];
  __shared__ float Ds[2][16][2];
  float hst[NN];
  #pragma unroll
  for (int i = 0; i < NN; i++) hst[i] = 0.f;
  float Dv = Dvec[h];
  long row0 = (long)b * L;
  int nchunks = L / 16;
  const int xs_s = tid / (PP / 4);
  const int xs_o = (tid % (PP / 4)) * 4;
  const int bc_s = tid >> 5, bc_o = (tid & 31) * 4;
  float4 xr = make_float4(0, 0, 0, 0), bc0 = xr, bc1 = xr;
  float dval = 0.f;

  auto issue = [&](long t0) {
    if (tid < XT)
      xr = *reinterpret_cast<const float4*>(
          &xbc[(t0 + xs_s) * conv_dim + (h << 6) + ns * PP + xs_o]);
    bc0 = *reinterpret_cast<const float4*>(&xbc[(t0 + bc_s) * conv_dim + d_inner + bc_o]);
    bc1 = *reinterpret_cast<const float4*>(&xbc[(t0 + 8 + bc_s) * conv_dim + d_inner + bc_o]);
    if (tid < 32) dval = ((tid & 1) ? da : dt)[(t0 + (tid >> 1)) * H + h];
  };
  auto commit = [&](int buf) {
    if (tid < XT) *reinterpret_cast<float4*>(&Xs[buf][xs_s][xs_o]) = xr;
    *reinterpret_cast<float4*>(&BCs[buf][bc_s][bc_o]) = bc0;
    *reinterpret_cast<float4*>(&BCs[buf][8 + bc_s][bc_o]) = bc1;
    if (tid < 32) Ds[buf][tid >> 1][tid & 1] = dval;
  };

  issue(row0);
  commit(0);
  __syncthreads();

  for (int c = 0; c < nchunks; ++c) {
    int buf = c & 1;
    if (c + 1 < nchunks) issue(row0 + (long)(c + 1) * 16);
    float yvs[16], xhs[16];
    // pure compute loop: no cross-lane ops, DS reads pipeline freely
    #pragma unroll
    for (int t = 0; t < 16; ++t) {
      float2 dd = *reinterpret_cast<const float2*>(&Ds[buf][t][0]);
      float xh = Xs[buf][t][pl];
      float dtx = dd.x * xh;
      float dav = dd.y;
      const float4* Bp = reinterpret_cast<const float4*>(&BCs[buf][t][n0]);
      const float4* Cp = reinterpret_cast<const float4*>(&BCs[buf][t][64 + n0]);
      float yv = 0.f;
      #pragma unroll
      for (int q = 0; q < NV; q++) {
        float4 bv = Bp[q], cv = Cp[q];
        hst[q * 4 + 0] = dav * hst[q * 4 + 0] + dtx * bv.x; yv += hst[q * 4 + 0] * cv.x;
        hst[q * 4 + 1] = dav * hst[q * 4 + 1] + dtx * bv.y; yv += hst[q * 4 + 1] * cv.y;
        hst[q * 4 + 2] = dav * hst[q * 4 + 2] + dtx * bv.z; yv += hst[q * 4 + 2] * cv.z;
        hst[q * 4 + 3] = dav * hst[q * 4 + 3] + dtx * bv.w; yv += hst[q * 4 + 3] * cv.w;
      }
      yvs[t] = yv;
      xhs[t] = xh;
    }
    // deferred reductions: 16 independent shuffle chains
    #pragma unroll
    for (int t = 0; t < 16; ++t) {
      float yv = yvs[t];
      #pragma unroll
      for (int o = 1; o < G; o <<= 1) yv += __shfl_xor(yv, o);
      yvs[t] = yv;
    }
    if (nc == 0) {
      #pragma unroll
      for (int t = 0; t < 16; ++t)
        y[(row0 + c * 16 + t) * d_inner + (h << 6) + ns * PP + pl] =
            yvs[t] + Dv * xhs[t];
    }
    __syncthreads();
    if (c + 1 < nchunks) {
      commit(buf ^ 1);
      __syncthreads();
    }
  }
}

// --------- g = y*silu(z); g *= rsqrt(mean(g^2)+eps)*rms_w (in place) ---------
template <int NJ>
__global__ __launch_bounds__(256) void gate_rms(float* __restrict__ y,
                                                const float* __restrict__ zx,
                                                const float* __restrict__ rmsw,
                                                int d_inner, int ld) {
  long row = blockIdx.x;
  float* yr = y + row * d_inner;
  const float* zr = zx + row * ld;
  __shared__ float lds[4];
  float g[NJ];
  float ss = 0.f;
  #pragma unroll
  for (int j = 0; j < NJ; j++) {
    int c = threadIdx.x + (j << 8);
    float gv = yr[c] * siluf(zr[c]);
    g[j] = gv;
    ss += gv * gv;
  }
  float tot = block_sum(ss, lds);
  float inv = rsqrtf(tot / (float)d_inner + EPSV);
  #pragma unroll
  for (int j = 0; j < NJ; j++) {
    int c = threadIdx.x + (j << 8);
    yr[c] = g[j] * inv * rmsw[c];
  }
}

extern "C" void kernel_launch(void* const* d_in, const int* in_sizes, int n_in,
                              void* d_out, int out_size, void* d_ws,
                              size_t ws_size, hipStream_t stream) {
  const float* x        = (const float*)d_in[0];
  const float* ln_spa_w = (const float*)d_in[1];
  const float* ln_spa_b = (const float*)d_in[2];
  const float* ln_spe_w = (const float*)d_in[3];
  const float* ln_spe_b = (const float*)d_in[4];
  const float* spa_W_in   = (const float*)d_in[5];
  const float* spa_conv_w = (const float*)d_in[6];
  const float* spa_conv_b = (const float*)d_in[7];
  const float* spa_dt_b   = (const float*)d_in[8];
  const float* spa_A_log  = (const float*)d_in[9];
  const float* spa_D      = (const float*)d_in[10];
  const float* spa_rms_w  = (const float*)d_in[11];
  const float* spa_W_out  = (const float*)d_in[12];
  const float* spe_W_in   = (const float*)d_in[13];
  const float* spe_conv_w = (const float*)d_in[14];
  const float* spe_conv_b = (const float*)d_in[15];
  const float* spe_dt_b   = (const float*)d_in[16];
  const float* spe_A_log  = (const float*)d_in[17];
  const float* spe_D      = (const float*)d_in[18];
  const float* spe_rms_w  = (const float*)d_in[19];
  const float* spe_W_out  = (const float*)d_in[20];
  float* out = (float*)d_out;

  float* ws = (float*)d_ws;
  float* xspa = ws;                    // 1,048,576 floats (persists across phases)
  float* S = ws + 1048576;             // shared scratch region

  // ---------- spatial mamba (seq len 1024, d_model 128) ----------
  float* xn  = S;                      // 1,048,576
  float* zx  = S + 1048576;            // 5,275,648
  float* cv  = zx + 5275648;           // 3,145,728
  float* dtb = cv + 3145728;           // 32,768
  float* dab = dtb + 32768;            // 32,768
  float* yb  = dab + 32768;            // 2,097,152

  hipLaunchKernelGGL(ln_rows128, dim3(8192), dim3(256), 0, stream,
                     x, ln_spa_w, ln_spa_b, xn);
  hipLaunchKernelGGL((gemm64<0>), dim3(11, 128), dim3(256), 0, stream,
                     xn, spa_W_in, nullptr, zx, 8192, 644, 128);
  hipLaunchKernelGGL(conv_silu, dim3((8 * 1024 * 384 + 255) / 256), dim3(256), 0,
                     stream, zx, spa_conv_w, spa_conv_b, cv, 8, 1024, 384, 644, 256);
  hipLaunchKernelGGL(dtda_kernel, dim3((8192 * 4 + 255) / 256), dim3(256), 0,
                     stream, zx, spa_dt_b, spa_A_log, dtb, dab, 8192, 4, 644, 640);
  // G=16 (4 n/thread), p split across 4 blocks: grid = 8*4*4 = 128
  hipLaunchKernelGGL((scan_v4<16, 4>), dim3(128), dim3(256), 0, stream,
                     cv, dtb, dab, spa_D, yb, 1024, 4, 384, 256);
  hipLaunchKernelGGL((gate_rms<1>), dim3(8192), dim3(256), 0, stream,
                     yb, zx, spa_rms_w, 256, 644);
  hipLaunchKernelGGL((gemm64<1>), dim3(2, 128), dim3(256), 0, stream,
                     yb, spa_W_out, x, xspa, 8192, 128, 256);

  // ---------- spectral mamba (seq len 128, d_model 1024) ----------
  float* xn2  = S;                     // 1,048,576
  float* zx2  = S + 1048576;           // 4,358,144
  float* cv2  = zx2 + 4358144;         // 2,228,224
  float* dtb2 = cv2 + 2228224;         // 32,768
  float* dab2 = dtb2 + 32768;          // 32,768
  float* yb2  = dab2 + 32768;          // 2,097,152

  hipLaunchKernelGGL(ln_spe_t, dim3(1024), dim3(256), 0, stream,
                     xspa, ln_spe_w, ln_spe_b, xn2);

  // -- spe W_in GEMM in bf16 MFMA; scratch overlays dead cv2..yb2 region --
  unsigned short* Abf   = (unsigned short*)cv2;            // 1024*1024 bf16
  unsigned short* Wt_in = (unsigned short*)(cv2 + 524288); // 4256*1024 bf16
  hipLaunchKernelGGL(f2bf4, dim3(1024), dim3(256), 0, stream,
                     xn2, Abf, (long)262144);
  hipLaunchKernelGGL(wtconv, dim3(67, 16), dim3(256), 0, stream,
                     spe_W_in, Wt_in, 1024, 4256);
  hipLaunchKernelGGL((gemm_mfma<0>), dim3(67, 16), dim3(256), 0, stream,
                     Abf, Wt_in, nullptr, zx2, 1024, 4256, 1024);

  hipLaunchKernelGGL(conv_silu, dim3((8 * 128 * 2176 + 255) / 256), dim3(256), 0,
                     stream, zx2, spe_conv_w, spe_conv_b, cv2, 8, 128, 2176, 4256, 2048);
  hipLaunchKernelGGL(dtda_kernel, dim3((1024 * 32 + 255) / 256), dim3(256), 0,
                     stream, zx2, spe_dt_b, spe_A_log, dtb2, dab2, 1024, 32, 4256, 4224);
  hipLaunchKernelGGL((scan_v4<4, 1>), dim3(256), dim3(256), 0, stream,
                     cv2, dtb2, dab2, spe_D, yb2, 128, 32, 2176, 2048);
  hipLaunchKernelGGL((gate_rms<8>), dim3(1024), dim3(256), 0, stream,
                     yb2, zx2, spe_rms_w, 2048, 4256);

  // -- spe W_out GEMM in bf16 MFMA; scratch fits inside dead cv2 --
  unsigned short* Abf2   = (unsigned short*)cv2;             // 1024*2048 bf16
  unsigned short* Wt_out = (unsigned short*)(cv2 + 1048576); // 1024*2048 bf16
  hipLaunchKernelGGL(f2bf4, dim3(2048), dim3(256), 0, stream,
                     yb2, Abf2, (long)524288);
  hipLaunchKernelGGL(wtconv, dim3(16, 32), dim3(256), 0, stream,
                     spe_W_out, Wt_out, 2048, 1024);
  hipLaunchKernelGGL((gemm_mfma<2>), dim3(16, 16), dim3(256), 0, stream,
                     Abf2, Wt_out, xspa, out, 1024, 1024, 2048);
}

// Round 5
// 249.972 us; speedup vs baseline: 4.1517x; 1.4011x over previous
//
#include <hip/hip_runtime.h>
#include <hip/hip_bf16.h>

#define EPSV 1e-5f

typedef __attribute__((ext_vector_type(8))) short short8v;   // 8 bf16 in 4 VGPRs
typedef __attribute__((ext_vector_type(4))) float f32x4;

__device__ inline unsigned short f2bf(float f) {
  __hip_bfloat16 h = __float2bfloat16(f);
  return *reinterpret_cast<unsigned short*>(&h);
}

// ---------------- block-wide sum (256 threads = 4 waves) ----------------
__device__ inline float block_sum(float v, float* lds) {
  #pragma unroll
  for (int o = 32; o; o >>= 1) v += __shfl_xor(v, o);
  int tid = threadIdx.x;
  if ((tid & 63) == 0) lds[tid >> 6] = v;
  __syncthreads();
  float r = lds[0] + lds[1] + lds[2] + lds[3];
  __syncthreads();
  return r;
}

__device__ inline float siluf(float x) { return x / (1.f + expf(-x)); }

// inclusive prefix sum over 64 lanes (call from wave 0 only)
__device__ inline float wave_prefix_incl(float v, int lane) {
  #pragma unroll
  for (int o = 1; o < 64; o <<= 1) {
    float u = __shfl_up(v, o);
    if (lane >= o) v += u;
  }
  return v;
}

// ---------------- LayerNorm over rows of length 128 ----------------
__global__ __launch_bounds__(256) void ln_rows128(const float* __restrict__ x,
                                                  const float* __restrict__ w,
                                                  const float* __restrict__ bb,
                                                  float* __restrict__ out) {
  long row = blockIdx.x;
  int tid = threadIdx.x;
  __shared__ float lds[4];
  const float* xr = x + row * 128;
  float v = (tid < 128) ? xr[tid] : 0.f;
  float m = block_sum(v, lds) * (1.f / 128.f);
  float d = (tid < 128) ? (v - m) : 0.f;
  float var = block_sum(d * d, lds) * (1.f / 128.f);
  float inv = rsqrtf(var + EPSV);
  if (tid < 128) out[row * 128 + tid] = (v - m) * inv * w[tid] + bb[tid];
}

// ------- LayerNorm over L=1024 of transposed x_spa: row r=(b, ch) -------
__global__ __launch_bounds__(256) void ln_spe_t(const float* __restrict__ xspa,
                                                const float* __restrict__ w,
                                                const float* __restrict__ bb,
                                                float* __restrict__ out) {
  int r = blockIdx.x;
  int b = r >> 7, ch = r & 127;
  int tid = threadIdx.x;
  __shared__ float lds[4];
  float xr[4];
  float s = 0.f;
  #pragma unroll
  for (int j = 0; j < 4; j++) {
    int l = tid + (j << 8);
    xr[j] = xspa[((long)b * 1024 + l) * 128 + ch];
    s += xr[j];
  }
  float m = block_sum(s, lds) * (1.f / 1024.f);
  float s2 = 0.f;
  #pragma unroll
  for (int j = 0; j < 4; j++) { float d = xr[j] - m; s2 += d * d; }
  float var = block_sum(s2, lds) * (1.f / 1024.f);
  float inv = rsqrtf(var + EPSV);
  #pragma unroll
  for (int j = 0; j < 4; j++) {
    int l = tid + (j << 8);
    out[(long)r * 1024 + l] = (xr[j] - m) * inv * w[l] + bb[l];
  }
}

// ---------------- fp32 -> bf16 elementwise convert (float4 granularity) ----------------
__global__ __launch_bounds__(256) void f2bf4(const float* __restrict__ in,
                                             unsigned short* __restrict__ out,
                                             long n4) {
  long i = (long)blockIdx.x * 256 + threadIdx.x;
  if (i >= n4) return;
  float4 v = reinterpret_cast<const float4*>(in)[i];
  ushort4 o;
  o.x = f2bf(v.x); o.y = f2bf(v.y); o.z = f2bf(v.z); o.w = f2bf(v.w);
  reinterpret_cast<ushort4*>(out)[i] = o;
}

// ------- W[K][N] fp32 -> Wt[N][K] bf16 (LDS-tiled transpose-convert) -------
// grid: ((N+63)/64, K/64); K % 64 == 0, N % 4 == 0.
__global__ __launch_bounds__(256) void wtconv(const float* __restrict__ W,
                                              unsigned short* __restrict__ Wt,
                                              int K, int N) {
  __shared__ float tile[64][65];
  int n0 = blockIdx.x * 64, k0 = blockIdx.y * 64;
  int tid = threadIdx.x;
  int r = tid >> 4, c4 = (tid & 15) * 4;
  #pragma unroll
  for (int i = 0; i < 4; i++) {
    int kk = r + i * 16;
    float4 v = make_float4(0.f, 0.f, 0.f, 0.f);
    if (n0 + c4 < N) v = *reinterpret_cast<const float4*>(&W[(long)(k0 + kk) * N + n0 + c4]);
    tile[kk][c4] = v.x; tile[kk][c4 + 1] = v.y; tile[kk][c4 + 2] = v.z; tile[kk][c4 + 3] = v.w;
  }
  __syncthreads();
  #pragma unroll
  for (int i = 0; i < 4; i++) {
    int nl = r + i * 16;
    if (n0 + nl < N) {
      ushort4 o;
      o.x = f2bf(tile[c4 + 0][nl]);
      o.y = f2bf(tile[c4 + 1][nl]);
      o.z = f2bf(tile[c4 + 2][nl]);
      o.w = f2bf(tile[c4 + 3][nl]);
      *reinterpret_cast<ushort4*>(&Wt[(long)(n0 + nl) * K + k0 + c4]) = o;
    }
  }
}

// ---------------- bf16 MFMA GEMM: out[M,N] = A[M,K] @ Bt[N,K]^T ----------------
// MODE 0: plain. MODE 1: out = v + R (same layout).
// MODE 2: transposed add (spe W_out): r=(b,ch) b=r>>7 ch=r&127;
//         out[b][c][ch] = v + R[b][c][ch].
// MODE 3: column-split: c<c1 -> out (ld c1); c<c2 -> o2 (ld c2-c1); else o3 (ld N-c2).
template <int MODE>
__global__ __launch_bounds__(256) void gemm_mfma(const unsigned short* __restrict__ A,
                                                 const unsigned short* __restrict__ Bt,
                                                 const float* __restrict__ R,
                                                 float* __restrict__ out,
                                                 float* __restrict__ o2,
                                                 float* __restrict__ o3,
                                                 int M, int N, int K,
                                                 int c1, int c2) {
  __shared__ unsigned short As[64 * 40];   // rows padded 32->40 bf16
  __shared__ unsigned short Bs[64 * 40];
  int tid = threadIdx.x;
  int lane = tid & 63, w = tid >> 6;
  int wr = (w >> 1) * 32, wc = (w & 1) * 32;
  int ln15 = lane & 15, kg = lane >> 4;
  int rowBase = blockIdx.y * 64, colBase = blockIdx.x * 64;
  int sm = tid >> 2, skb = (tid & 3) * 8;
  f32x4 acc[2][2] = {};
  for (int k0 = 0; k0 < K; k0 += 32) {
    {
      short8v av = *reinterpret_cast<const short8v*>(&A[(long)(rowBase + sm) * K + k0 + skb]);
      *reinterpret_cast<short8v*>(&As[sm * 40 + skb]) = av;
      int n = colBase + sm;
      short8v bv = {0, 0, 0, 0, 0, 0, 0, 0};
      if (n < N) bv = *reinterpret_cast<const short8v*>(&Bt[(long)n * K + k0 + skb]);
      *reinterpret_cast<short8v*>(&Bs[sm * 40 + skb]) = bv;
    }
    __syncthreads();
    short8v af[2], bfr[2];
    #pragma unroll
    for (int mt = 0; mt < 2; mt++)
      af[mt] = *reinterpret_cast<const short8v*>(&As[(wr + mt * 16 + ln15) * 40 + kg * 8]);
    #pragma unroll
    for (int nt = 0; nt < 2; nt++)
      bfr[nt] = *reinterpret_cast<const short8v*>(&Bs[(wc + nt * 16 + ln15) * 40 + kg * 8]);
    #pragma unroll
    for (int mt = 0; mt < 2; mt++)
      #pragma unroll
      for (int nt = 0; nt < 2; nt++)
        acc[mt][nt] = __builtin_amdgcn_mfma_f32_16x16x32_bf16(af[mt], bfr[nt], acc[mt][nt], 0, 0, 0);
    __syncthreads();
  }
  #pragma unroll
  for (int mt = 0; mt < 2; mt++)
    #pragma unroll
    for (int nt = 0; nt < 2; nt++)
      #pragma unroll
      for (int q = 0; q < 4; q++) {
        int r = rowBase + wr + mt * 16 + kg * 4 + q;
        int c = colBase + wc + nt * 16 + ln15;
        if (c < N) {
          float v = acc[mt][nt][q];
          if (MODE == 0) {
            out[(long)r * N + c] = v;
          } else if (MODE == 1) {
            out[(long)r * N + c] = v + R[(long)r * N + c];
          } else if (MODE == 2) {
            int bb = r >> 7, ch = r & 127;
            out[(long)bb * 131072 + (long)c * 128 + ch] =
                v + R[((long)bb * 1024 + c) * 128 + ch];
          } else {
            if (c < c1) out[(long)r * c1 + c] = v;
            else if (c < c2) o2[(long)r * (c2 - c1) + (c - c1)] = v;
            else o3[(long)r * (N - c2) + (c - c2)] = v;
          }
        }
      }
}

// ------------- causal depthwise conv (D_CONV=4) + bias + SiLU -------------
__global__ __launch_bounds__(256) void conv_silu(const float* __restrict__ zx,
                                                 const float* __restrict__ cw,
                                                 const float* __restrict__ cb,
                                                 float* __restrict__ out,
                                                 int Bb, int L, int conv_dim) {
  long idx = (long)blockIdx.x * 256 + threadIdx.x;
  long total = (long)Bb * L * conv_dim;
  if (idx >= total) return;
  int ch = (int)(idx % conv_dim);
  long rt = idx / conv_dim;
  int t = (int)(rt % L);
  int b = (int)(rt / L);
  float acc = cb[ch];
  #pragma unroll
  for (int k = 0; k < 4; k++) {
    int tt = t + k - 3;
    if (tt >= 0)
      acc += cw[k * conv_dim + ch] * zx[((long)b * L + tt) * conv_dim + ch];
  }
  out[idx] = siluf(acc);
}

// ------- dt = softplus(raw + bias); la = dt * A = -exp(A_log)*dt (log-decay) -------
__global__ __launch_bounds__(256) void dtda_kernel(const float* __restrict__ raw,
                                                   const float* __restrict__ dtbias,
                                                   const float* __restrict__ alog,
                                                   float* __restrict__ dt,
                                                   float* __restrict__ la,
                                                   int rows, int H) {
  int idx = blockIdx.x * 256 + threadIdx.x;
  if (idx >= rows * H) return;
  int h = idx % H;
  long row = idx / H;
  float v = raw[row * H + h] + dtbias[h];
  float sp = (v > 20.f) ? v : log1pf(expf(v));
  dt[idx] = sp;
  la[idx] = -expf(alog[h]) * sp;
}

// ===================== chunked SSD (T=64 per chunk) =====================
// K1: per (b,h,chunk) compute chunk-state contribution
//   S_c[p,n] = sum_t exp(cumT - cum[t]) * dt[t] * x[t,p] * B[t,n]
// and A_c = exp(cumT). Fully parallel over chunks.
__global__ __launch_bounds__(256) void ssd_local(const float* __restrict__ xbc,
                                                 const float* __restrict__ dtv,
                                                 const float* __restrict__ la,
                                                 float* __restrict__ Sc,
                                                 float* __restrict__ Aprod,
                                                 int NC, int H, int conv_dim,
                                                 int d_inner) {
  int blk = blockIdx.x;
  int c = blk % NC, bh = blk / NC;
  int h = bh % H, b = bh / H;
  int tid = threadIdx.x;
  long row0 = ((long)(b * NC + c)) * 64;
  __shared__ float Xs[64][64];
  __shared__ float Bs[64][64];
  __shared__ float Ws[64];
  int tq = tid >> 4, cq = (tid & 15) << 2;
  #pragma unroll
  for (int i = 0; i < 4; i++) {
    int t = tq + i * 16;
    const float* rp = xbc + (row0 + t) * conv_dim;
    *reinterpret_cast<f32x4*>(&Xs[t][cq]) =
        *reinterpret_cast<const f32x4*>(rp + (h << 6) + cq);
    *reinterpret_cast<f32x4*>(&Bs[t][cq]) =
        *reinterpret_cast<const f32x4*>(rp + d_inner + cq);
  }
  if (tid < 64) {
    long r = (row0 + tid) * H + h;
    float cum = wave_prefix_incl(la[r], tid);
    float cT = __shfl(cum, 63);
    Ws[tid] = expf(cT - cum) * dtv[r];
    if (tid == 63) Aprod[blk] = expf(cT);
  }
  __syncthreads();
  int p0 = (tid >> 4) << 2, n0 = (tid & 15) << 2;
  f32x4 S0 = {0.f, 0.f, 0.f, 0.f}, S1 = S0, S2 = S0, S3 = S0;
  for (int t = 0; t < 64; t++) {
    float w = Ws[t];
    f32x4 xv = *reinterpret_cast<const f32x4*>(&Xs[t][p0]);
    f32x4 bv = *reinterpret_cast<const f32x4*>(&Bs[t][n0]);
    S0 += bv * (w * xv[0]);
    S1 += bv * (w * xv[1]);
    S2 += bv * (w * xv[2]);
    S3 += bv * (w * xv[3]);
  }
  float* base = Sc + (long)blk * 4096;
  *reinterpret_cast<f32x4*>(&base[(p0 + 0) * 64 + n0]) = S0;
  *reinterpret_cast<f32x4*>(&base[(p0 + 1) * 64 + n0]) = S1;
  *reinterpret_cast<f32x4*>(&base[(p0 + 2) * 64 + n0]) = S2;
  *reinterpret_cast<f32x4*>(&base[(p0 + 3) * 64 + n0]) = S3;
}

// K2: sequential carry over chunk states; rewrites Sc[c] with h_prev (state
// BEFORE chunk c): h = A_c * h + S_c. Only NC sequential steps.
__global__ __launch_bounds__(256) void ssd_carry(float* __restrict__ Sc,
                                                 const float* __restrict__ Aprod,
                                                 int NC) {
  int bh = blockIdx.x, tid = threadIdx.x;
  int p0 = (tid >> 4) << 2, n0 = (tid & 15) << 2;
  f32x4 h0 = {0.f, 0.f, 0.f, 0.f}, h1 = h0, h2 = h0, h3 = h0;
  for (int c = 0; c < NC; c++) {
    float* base = Sc + ((long)bh * NC + c) * 4096;
    float a = Aprod[bh * NC + c];
    f32x4 s0 = *reinterpret_cast<f32x4*>(&base[(p0 + 0) * 64 + n0]);
    f32x4 s1 = *reinterpret_cast<f32x4*>(&base[(p0 + 1) * 64 + n0]);
    f32x4 s2 = *reinterpret_cast<f32x4*>(&base[(p0 + 2) * 64 + n0]);
    f32x4 s3 = *reinterpret_cast<f32x4*>(&base[(p0 + 3) * 64 + n0]);
    *reinterpret_cast<f32x4*>(&base[(p0 + 0) * 64 + n0]) = h0;
    *reinterpret_cast<f32x4*>(&base[(p0 + 1) * 64 + n0]) = h1;
    *reinterpret_cast<f32x4*>(&base[(p0 + 2) * 64 + n0]) = h2;
    *reinterpret_cast<f32x4*>(&base[(p0 + 3) * 64 + n0]) = h3;
    h0 = h0 * a + s0;
    h1 = h1 * a + s1;
    h2 = h2 * a + s2;
    h3 = h3 * a + s3;
  }
}

// K3: per (b,h,chunk) compute outputs:
// y[t,p] = sum_{s<=t} exp(cum[t]-cum[s])*dt[s]*(C[t]·B[s])*x[s,p]
//        + exp(cum[t]) * (C[t]·hprev[p,:]) + D*x[t,p]
__global__ __launch_bounds__(256) void ssd_out(const float* __restrict__ xbc,
                                               const float* __restrict__ dtv,
                                               const float* __restrict__ la,
                                               const float* __restrict__ Hp,
                                               const float* __restrict__ Dvec,
                                               float* __restrict__ y,
                                               int NC, int H, int conv_dim,
                                               int d_inner) {
  int blk = blockIdx.x;
  int c = blk % NC, bh = blk / NC;
  int h = bh % H, b = bh / H;
  int tid = threadIdx.x;
  long row0 = ((long)(b * NC + c)) * 64;
  __shared__ float CsT[64 * 68];   // [n][t]
  __shared__ float shB[64 * 68];   // BsT[n][s]  -> GmT[s][t]
  __shared__ float shX[64 * 68];   // Xs[s][p]   -> HpT[n][p]
  __shared__ float Cum[64], Dt[64];
  int tq = tid >> 4, cq = (tid & 15) << 2;
  #pragma unroll
  for (int i = 0; i < 4; i++) {
    int t = tq + i * 16;
    const float* rp = xbc + (row0 + t) * conv_dim;
    f32x4 cv = *reinterpret_cast<const f32x4*>(rp + d_inner + 64 + cq);
    f32x4 bv = *reinterpret_cast<const f32x4*>(rp + d_inner + cq);
    f32x4 xv = *reinterpret_cast<const f32x4*>(rp + (h << 6) + cq);
    #pragma unroll
    for (int j = 0; j < 4; j++) {
      CsT[(cq + j) * 68 + t] = cv[j];
      shB[(cq + j) * 68 + t] = bv[j];
    }
    *reinterpret_cast<f32x4*>(&shX[t * 68 + cq]) = xv;
  }
  if (tid < 64) {
    long r = (row0 + tid) * H + h;
    Cum[tid] = wave_prefix_incl(la[r], tid);
    Dt[tid] = dtv[r];
  }
  __syncthreads();
  int t0 = (tid >> 4) << 2, q0 = (tid & 15) << 2;  // q0 = s in A, p in B/C
  // Phase A: G[t,s] = sum_n C[t,n] B[s,n]; Gj holds t-quad for s = q0+j
  f32x4 G0 = {0.f, 0.f, 0.f, 0.f}, G1 = G0, G2 = G0, G3 = G0;
  for (int n = 0; n < 64; n++) {
    f32x4 cv = *reinterpret_cast<const f32x4*>(&CsT[n * 68 + t0]);
    f32x4 bv = *reinterpret_cast<const f32x4*>(&shB[n * 68 + q0]);
    G0 += cv * bv[0];
    G1 += cv * bv[1];
    G2 += cv * bv[2];
    G3 += cv * bv[3];
  }
  // mask + weight (register-only; uses Cum/Dt)
  f32x4 gm[4] = {G0, G1, G2, G3};
  #pragma unroll
  for (int j = 0; j < 4; j++) {
    int s = q0 + j;
    float ds = Dt[s], cs = Cum[s];
    #pragma unroll
    for (int i = 0; i < 4; i++) {
      int t = t0 + i;
      gm[j][i] = (s <= t) ? gm[j][i] * expf(Cum[t] - cs) * ds : 0.f;
    }
  }
  __syncthreads();   // everyone done reading BsT
  #pragma unroll
  for (int j = 0; j < 4; j++)
    *reinterpret_cast<f32x4*>(&shB[(q0 + j) * 68 + t0]) = gm[j];  // GmT[s][t]
  __syncthreads();
  // Phase B: Y[i][j] = sum_s Gm[t0+i,s] * x[s, q0+j]
  f32x4 Y0 = {0.f, 0.f, 0.f, 0.f}, Y1 = Y0, Y2 = Y0, Y3 = Y0;  // Yi over p
  for (int s = 0; s < 64; s++) {
    f32x4 g4 = *reinterpret_cast<const f32x4*>(&shB[s * 68 + t0]);
    f32x4 x4 = *reinterpret_cast<const f32x4*>(&shX[s * 68 + q0]);
    Y0 += x4 * g4[0];
    Y1 += x4 * g4[1];
    Y2 += x4 * g4[2];
    Y3 += x4 * g4[3];
  }
  __syncthreads();   // done with Xs
  // stage hprev transposed: HpT[n][p]
  const float* hb = Hp + (long)blk * 4096;
  #pragma unroll
  for (int i = 0; i < 4; i++) {
    int p = tq + i * 16;
    f32x4 hv = *reinterpret_cast<const f32x4*>(&hb[p * 64 + cq]);
    #pragma unroll
    for (int j = 0; j < 4; j++) shX[(cq + j) * 68 + p] = hv[j];
  }
  __syncthreads();
  // Phase C: Z[i][j] = sum_n C[t0+i,n] * hprev[q0+j,n]
  f32x4 Z0 = {0.f, 0.f, 0.f, 0.f}, Z1 = Z0, Z2 = Z0, Z3 = Z0;
  for (int n = 0; n < 64; n++) {
    f32x4 cv = *reinterpret_cast<const f32x4*>(&CsT[n * 68 + t0]);
    f32x4 hv = *reinterpret_cast<const f32x4*>(&shX[n * 68 + q0]);
    Z0 += hv * cv[0];
    Z1 += hv * cv[1];
    Z2 += hv * cv[2];
    Z3 += hv * cv[3];
  }
  // Phase D: finalize
  float Dv = Dvec[h];
  f32x4 Yv[4] = {Y0, Y1, Y2, Y3};
  f32x4 Zv[4] = {Z0, Z1, Z2, Z3};
  #pragma unroll
  for (int i = 0; i < 4; i++) {
    int t = t0 + i;
    float wB = expf(Cum[t]);
    const float* xp = xbc + (row0 + t) * conv_dim + (h << 6) + q0;
    f32x4 xg = *reinterpret_cast<const f32x4*>(xp);
    f32x4 o = Yv[i] + Zv[i] * wB + xg * Dv;
    *reinterpret_cast<f32x4*>(&y[(row0 + t) * d_inner + (h << 6) + q0]) = o;
  }
}

// --------- g = y*silu(z); g *= rsqrt(mean(g^2)+eps)*rms_w (in place) ---------
template <int NJ>
__global__ __launch_bounds__(256) void gate_rms(float* __restrict__ y,
                                                const float* __restrict__ z,
                                                const float* __restrict__ rmsw,
                                                int d_inner) {
  long row = blockIdx.x;
  float* yr = y + row * d_inner;
  const float* zr = z + row * d_inner;
  __shared__ float lds[4];
  float g[NJ];
  float ss = 0.f;
  #pragma unroll
  for (int j = 0; j < NJ; j++) {
    int c = threadIdx.x + (j << 8);
    float gv = yr[c] * siluf(zr[c]);
    g[j] = gv;
    ss += gv * gv;
  }
  float tot = block_sum(ss, lds);
  float inv = rsqrtf(tot / (float)d_inner + EPSV);
  #pragma unroll
  for (int j = 0; j < NJ; j++) {
    int c = threadIdx.x + (j << 8);
    yr[c] = g[j] * inv * rmsw[c];
  }
}

extern "C" void kernel_launch(void* const* d_in, const int* in_sizes, int n_in,
                              void* d_out, int out_size, void* d_ws,
                              size_t ws_size, hipStream_t stream) {
  const float* x        = (const float*)d_in[0];
  const float* ln_spa_w = (const float*)d_in[1];
  const float* ln_spa_b = (const float*)d_in[2];
  const float* ln_spe_w = (const float*)d_in[3];
  const float* ln_spe_b = (const float*)d_in[4];
  const float* spa_W_in   = (const float*)d_in[5];
  const float* spa_conv_w = (const float*)d_in[6];
  const float* spa_conv_b = (const float*)d_in[7];
  const float* spa_dt_b   = (const float*)d_in[8];
  const float* spa_A_log  = (const float*)d_in[9];
  const float* spa_D      = (const float*)d_in[10];
  const float* spa_rms_w  = (const float*)d_in[11];
  const float* spa_W_out  = (const float*)d_in[12];
  const float* spe_W_in   = (const float*)d_in[13];
  const float* spe_conv_w = (const float*)d_in[14];
  const float* spe_conv_b = (const float*)d_in[15];
  const float* spe_dt_b   = (const float*)d_in[16];
  const float* spe_A_log  = (const float*)d_in[17];
  const float* spe_D      = (const float*)d_in[18];
  const float* spe_rms_w  = (const float*)d_in[19];
  const float* spe_W_out  = (const float*)d_in[20];
  float* out = (float*)d_out;

  float* ws = (float*)d_ws;
  float* xspa = ws;                 // 1,048,576 (persists across phases)
  float* S = ws + 1048576;
  // layout (floats), total 11,632,640 == proven budget:
  float* xn     = S;                // 1,048,576
  float* z      = S + 1048576;      // 2,097,152
  float* xbcraw = S + 3145728;      // 3,145,728 (later: Sc / Wt2_spa)
  float* dtraw  = S + 6291456;      // 32,768   (later: Aprod)
  float* cv     = S + 6324224;      // 3,145,728 (also bf16 scratch)
  float* dtb    = S + 9469952;      // 32,768
  float* la     = S + 9502720;      // 32,768
  float* yb     = S + 9535488;      // 2,097,152

  // ================= spatial mamba (L=1024, d_model=128) =================
  hipLaunchKernelGGL(ln_rows128, dim3(8192), dim3(256), 0, stream,
                     x, ln_spa_w, ln_spa_b, xn);
  // W_in GEMM (bf16 MFMA, split z|xBC|dt); scratch in dead cv region
  unsigned short* Abf_spa = (unsigned short*)cv;             // 8192x128 bf16
  unsigned short* Wt_spa  = (unsigned short*)(cv + 524288);  // 644x128 bf16
  hipLaunchKernelGGL(f2bf4, dim3(1024), dim3(256), 0, stream,
                     xn, Abf_spa, (long)262144);
  hipLaunchKernelGGL(wtconv, dim3(11, 2), dim3(256), 0, stream,
                     spa_W_in, Wt_spa, 128, 644);
  hipLaunchKernelGGL((gemm_mfma<3>), dim3(11, 128), dim3(256), 0, stream,
                     Abf_spa, Wt_spa, nullptr, z, xbcraw, dtraw,
                     8192, 644, 128, 256, 640);
  hipLaunchKernelGGL(conv_silu, dim3(12288), dim3(256), 0, stream,
                     xbcraw, spa_conv_w, spa_conv_b, cv, 8, 1024, 384);
  hipLaunchKernelGGL(dtda_kernel, dim3(128), dim3(256), 0, stream,
                     dtraw, spa_dt_b, spa_A_log, dtb, la, 8192, 4);
  // chunked SSD: NC=16 chunks of 64; Sc overlays xbcraw, Aprod overlays dtraw
  float* Sc_spa = xbcraw;
  float* Ap_spa = dtraw;
  hipLaunchKernelGGL(ssd_local, dim3(512), dim3(256), 0, stream,
                     cv, dtb, la, Sc_spa, Ap_spa, 16, 4, 384, 256);
  hipLaunchKernelGGL(ssd_carry, dim3(32), dim3(256), 0, stream,
                     Sc_spa, Ap_spa, 16);
  hipLaunchKernelGGL(ssd_out, dim3(512), dim3(256), 0, stream,
                     cv, dtb, la, Sc_spa, spa_D, yb, 16, 4, 384, 256);
  hipLaunchKernelGGL((gate_rms<1>), dim3(8192), dim3(256), 0, stream,
                     yb, z, spa_rms_w, 256);
  // W_out GEMM (bf16 MFMA) + residual
  unsigned short* Abf2_spa = (unsigned short*)xn;                  // 8192x256 bf16
  unsigned short* Wt2_spa  = (unsigned short*)(xbcraw + 2097152);  // 128x256 bf16
  hipLaunchKernelGGL(f2bf4, dim3(2048), dim3(256), 0, stream,
                     yb, Abf2_spa, (long)524288);
  hipLaunchKernelGGL(wtconv, dim3(2, 4), dim3(256), 0, stream,
                     spa_W_out, Wt2_spa, 256, 128);
  hipLaunchKernelGGL((gemm_mfma<1>), dim3(2, 128), dim3(256), 0, stream,
                     Abf2_spa, Wt2_spa, x, xspa, nullptr, nullptr,
                     8192, 128, 256, 0, 0);

  // ================= spectral mamba (L=128, d_model=1024) =================
  hipLaunchKernelGGL(ln_spe_t, dim3(1024), dim3(256), 0, stream,
                     xspa, ln_spe_w, ln_spe_b, xn);
  unsigned short* Abf_spe = (unsigned short*)yb;   // 1024x1024 bf16
  unsigned short* Wt_spe  = (unsigned short*)cv;   // 4256x1024 bf16
  hipLaunchKernelGGL(f2bf4, dim3(1024), dim3(256), 0, stream,
                     xn, Abf_spe, (long)262144);
  hipLaunchKernelGGL(wtconv, dim3(67, 16), dim3(256), 0, stream,
                     spe_W_in, Wt_spe, 1024, 4256);
  hipLaunchKernelGGL((gemm_mfma<3>), dim3(67, 16), dim3(256), 0, stream,
                     Abf_spe, Wt_spe, nullptr, z, xbcraw, dtraw,
                     1024, 4256, 1024, 2048, 4224);
  hipLaunchKernelGGL(conv_silu, dim3(8704), dim3(256), 0, stream,
                     xbcraw, spe_conv_w, spe_conv_b, cv, 8, 128, 2176);
  hipLaunchKernelGGL(dtda_kernel, dim3(128), dim3(256), 0, stream,
                     dtraw, spe_dt_b, spe_A_log, dtb, la, 1024, 32);
  float* Sc_spe = xbcraw;
  float* Ap_spe = dtraw;
  hipLaunchKernelGGL(ssd_local, dim3(512), dim3(256), 0, stream,
                     cv, dtb, la, Sc_spe, Ap_spe, 2, 32, 2176, 2048);
  hipLaunchKernelGGL(ssd_carry, dim3(256), dim3(256), 0, stream,
                     Sc_spe, Ap_spe, 2);
  hipLaunchKernelGGL(ssd_out, dim3(512), dim3(256), 0, stream,
                     cv, dtb, la, Sc_spe, spe_D, yb, 2, 32, 2176, 2048);
  hipLaunchKernelGGL((gate_rms<8>), dim3(1024), dim3(256), 0, stream,
                     yb, z, spe_rms_w, 2048);
  unsigned short* Abf2_spe = (unsigned short*)xn;  // 1024x2048 bf16
  unsigned short* Wt2_spe  = (unsigned short*)cv;  // 1024x2048 bf16
  hipLaunchKernelGGL(f2bf4, dim3(2048), dim3(256), 0, stream,
                     yb, Abf2_spe, (long)524288);
  hipLaunchKernelGGL(wtconv, dim3(16, 32), dim3(256), 0, stream,
                     spe_W_out, Wt2_spe, 2048, 1024);
  hipLaunchKernelGGL((gemm_mfma<2>), dim3(16, 16), dim3(256), 0, stream,
                     Abf2_spe, Wt2_spe, xspa, out, nullptr, nullptr,
                     1024, 1024, 2048, 0, 0);
}

// Round 6
// 223.207 us; speedup vs baseline: 4.6495x; 1.1199x over previous
//
#include <hip/hip_runtime.h>
#include <hip/hip_bf16.h>

#define EPSV 1e-5f

typedef __attribute__((ext_vector_type(8))) short short8v;   // 8 bf16 in 4 VGPRs
typedef __attribute__((ext_vector_type(4))) float f32x4;

__device__ inline unsigned short f2bf(float f) {
  __hip_bfloat16 h = __float2bfloat16(f);
  return *reinterpret_cast<unsigned short*>(&h);
}

// ---------------- block-wide sum (256 threads = 4 waves) ----------------
__device__ inline float block_sum(float v, float* lds) {
  #pragma unroll
  for (int o = 32; o; o >>= 1) v += __shfl_xor(v, o);
  int tid = threadIdx.x;
  if ((tid & 63) == 0) lds[tid >> 6] = v;
  __syncthreads();
  float r = lds[0] + lds[1] + lds[2] + lds[3];
  __syncthreads();
  return r;
}

__device__ inline float siluf(float x) { return x / (1.f + expf(-x)); }

// inclusive prefix sum over 64 lanes (call from wave 0 only)
__device__ inline float wave_prefix_incl(float v, int lane) {
  #pragma unroll
  for (int o = 1; o < 64; o <<= 1) {
    float u = __shfl_up(v, o);
    if (lane >= o) v += u;
  }
  return v;
}

// -------- LayerNorm over rows of length 128, emits bf16 directly --------
__global__ __launch_bounds__(256) void ln_rows128_bf16(const float* __restrict__ x,
                                                       const float* __restrict__ w,
                                                       const float* __restrict__ bb,
                                                       unsigned short* __restrict__ out) {
  long row = blockIdx.x;
  int tid = threadIdx.x;
  __shared__ float lds[4];
  const float* xr = x + row * 128;
  float v = (tid < 128) ? xr[tid] : 0.f;
  float m = block_sum(v, lds) * (1.f / 128.f);
  float d = (tid < 128) ? (v - m) : 0.f;
  float var = block_sum(d * d, lds) * (1.f / 128.f);
  float inv = rsqrtf(var + EPSV);
  if (tid < 128) out[row * 128 + tid] = f2bf((v - m) * inv * w[tid] + bb[tid]);
}

// ---- spe LN pass 1: per-(b,ch) mean/rstd over L=1024, coalesced reads ----
__global__ __launch_bounds__(256) void spe_stats(const float* __restrict__ xspa,
                                                 float* __restrict__ stats) {
  int b = blockIdx.x, tid = threadIdx.x;
  int ch = tid & 127, half = tid >> 7;
  const float* base = xspa + (long)b * 131072 + ch;
  float s = 0.f, q = 0.f;
  for (int l = half * 512; l < half * 512 + 512; l++) {
    float v = base[(long)l * 128];
    s += v; q += v * v;
  }
  __shared__ float S0[128], Q0[128];
  if (half == 0) { S0[ch] = s; Q0[ch] = q; }
  __syncthreads();
  if (half == 1) {
    float st = s + S0[ch], qt = q + Q0[ch];
    float m = st * (1.f / 1024.f);
    float var = qt * (1.f / 1024.f) - m * m;
    float2 mv; mv.x = m; mv.y = rsqrtf(var + EPSV);
    *reinterpret_cast<float2*>(&stats[(b * 128 + ch) * 2]) = mv;
  }
}

// ---- spe LN pass 2: normalize + transpose to [(b,ch)][l], emit bf16 ----
// grid: (2 ch-tiles of 64, 8 l-tiles of 128, 8 b)
__global__ __launch_bounds__(256) void spe_normT(const float* __restrict__ xspa,
                                                 const float* __restrict__ stats,
                                                 const float* __restrict__ w,
                                                 const float* __restrict__ bb,
                                                 unsigned short* __restrict__ out) {
  __shared__ float tile[128][65];
  int c0 = blockIdx.x * 64, l0 = blockIdx.y * 128, b = blockIdx.z;
  int tid = threadIdx.x;
  int rr = tid >> 4, c4 = (tid & 15) * 4;
  #pragma unroll
  for (int p = 0; p < 8; p++) {
    int l = rr + p * 16;
    f32x4 v = *reinterpret_cast<const f32x4*>(
        &xspa[((long)b * 1024 + l0 + l) * 128 + c0 + c4]);
    tile[l][c4] = v[0]; tile[l][c4 + 1] = v[1];
    tile[l][c4 + 2] = v[2]; tile[l][c4 + 3] = v[3];
  }
  __syncthreads();
  int ch = tid >> 2, lq = tid & 3;
  float2 mv = *reinterpret_cast<const float2*>(&stats[(b * 128 + c0 + ch) * 2]);
  #pragma unroll
  for (int j = 0; j < 8; j++) {
    int q = lq + j * 4;
    int l = q * 4;
    float4 wv = *reinterpret_cast<const float4*>(&w[l0 + l]);
    float4 bv = *reinterpret_cast<const float4*>(&bb[l0 + l]);
    ushort4 o;
    o.x = f2bf((tile[l + 0][ch] - mv.x) * mv.y * wv.x + bv.x);
    o.y = f2bf((tile[l + 1][ch] - mv.x) * mv.y * wv.y + bv.y);
    o.z = f2bf((tile[l + 2][ch] - mv.x) * mv.y * wv.z + bv.z);
    o.w = f2bf((tile[l + 3][ch] - mv.x) * mv.y * wv.w + bv.w);
    *reinterpret_cast<ushort4*>(&out[((long)b * 128 + c0 + ch) * 1024 + l0 + l]) = o;
  }
}

// ------- all 4 weight transposes W[K][N] -> Wt[N][K] bf16, one launch -------
__device__ inline void wtconv_tile(const float* __restrict__ W,
                                   unsigned short* __restrict__ Wt,
                                   int K, int N, int bx, int by) {
  __shared__ float tile[64][65];
  int n0 = bx * 64, k0 = by * 64;
  int tid = threadIdx.x;
  int r = tid >> 4, c4 = (tid & 15) * 4;
  #pragma unroll
  for (int i = 0; i < 4; i++) {
    int kk = r + i * 16;
    float4 v = make_float4(0.f, 0.f, 0.f, 0.f);
    if (n0 + c4 < N) v = *reinterpret_cast<const float4*>(&W[(long)(k0 + kk) * N + n0 + c4]);
    tile[kk][c4] = v.x; tile[kk][c4 + 1] = v.y; tile[kk][c4 + 2] = v.z; tile[kk][c4 + 3] = v.w;
  }
  __syncthreads();
  #pragma unroll
  for (int i = 0; i < 4; i++) {
    int nl = r + i * 16;
    if (n0 + nl < N) {
      ushort4 o;
      o.x = f2bf(tile[c4 + 0][nl]);
      o.y = f2bf(tile[c4 + 1][nl]);
      o.z = f2bf(tile[c4 + 2][nl]);
      o.w = f2bf(tile[c4 + 3][nl]);
      *reinterpret_cast<ushort4*>(&Wt[(long)(n0 + nl) * K + k0 + c4]) = o;
    }
  }
}

__global__ __launch_bounds__(256) void wtconv_all(const float* __restrict__ W0,
                                                  unsigned short* __restrict__ T0,
                                                  const float* __restrict__ W1,
                                                  unsigned short* __restrict__ T1,
                                                  const float* __restrict__ W2,
                                                  unsigned short* __restrict__ T2,
                                                  const float* __restrict__ W3,
                                                  unsigned short* __restrict__ T3) {
  int id = blockIdx.x;
  if (id < 22)        { int r = id;        wtconv_tile(W0, T0, 128,  644,  r % 11, r / 11); }
  else if (id < 30)   { int r = id - 22;   wtconv_tile(W1, T1, 256,  128,  r % 2,  r / 2); }
  else if (id < 1102) { int r = id - 30;   wtconv_tile(W2, T2, 1024, 4256, r % 67, r / 67); }
  else                { int r = id - 1102; wtconv_tile(W3, T3, 2048, 1024, r % 16, r / 16); }
}

// ---------------- bf16 MFMA GEMM: out[M,N] = A[M,K] @ Bt[N,K]^T ----------------
// MODE 1: out = v + R (same layout).
// MODE 2: transposed add (spe W_out): r=(b,ch) b=r>>7 ch=r&127;
//         out[b][c][ch] = v + R[b][c][ch].
// MODE 3: column-split: c<c1 -> out (ld c1); c<c2 -> o2 (ld c2-c1); else o3 (ld N-c2).
template <int MODE>
__global__ __launch_bounds__(256) void gemm_mfma(const unsigned short* __restrict__ A,
                                                 const unsigned short* __restrict__ Bt,
                                                 const float* __restrict__ R,
                                                 float* __restrict__ out,
                                                 float* __restrict__ o2,
                                                 float* __restrict__ o3,
                                                 int M, int N, int K,
                                                 int c1, int c2) {
  __shared__ unsigned short As[64 * 40];   // rows padded 32->40 bf16
  __shared__ unsigned short Bs[64 * 40];
  int tid = threadIdx.x;
  int lane = tid & 63, w = tid >> 6;
  int wr = (w >> 1) * 32, wc = (w & 1) * 32;
  int ln15 = lane & 15, kg = lane >> 4;
  int rowBase = blockIdx.y * 64, colBase = blockIdx.x * 64;
  int sm = tid >> 2, skb = (tid & 3) * 8;
  f32x4 acc[2][2] = {};
  for (int k0 = 0; k0 < K; k0 += 32) {
    {
      short8v av = *reinterpret_cast<const short8v*>(&A[(long)(rowBase + sm) * K + k0 + skb]);
      *reinterpret_cast<short8v*>(&As[sm * 40 + skb]) = av;
      int n = colBase + sm;
      short8v bv = {0, 0, 0, 0, 0, 0, 0, 0};
      if (n < N) bv = *reinterpret_cast<const short8v*>(&Bt[(long)n * K + k0 + skb]);
      *reinterpret_cast<short8v*>(&Bs[sm * 40 + skb]) = bv;
    }
    __syncthreads();
    short8v af[2], bfr[2];
    #pragma unroll
    for (int mt = 0; mt < 2; mt++)
      af[mt] = *reinterpret_cast<const short8v*>(&As[(wr + mt * 16 + ln15) * 40 + kg * 8]);
    #pragma unroll
    for (int nt = 0; nt < 2; nt++)
      bfr[nt] = *reinterpret_cast<const short8v*>(&Bs[(wc + nt * 16 + ln15) * 40 + kg * 8]);
    #pragma unroll
    for (int mt = 0; mt < 2; mt++)
      #pragma unroll
      for (int nt = 0; nt < 2; nt++)
        acc[mt][nt] = __builtin_amdgcn_mfma_f32_16x16x32_bf16(af[mt], bfr[nt], acc[mt][nt], 0, 0, 0);
    __syncthreads();
  }
  #pragma unroll
  for (int mt = 0; mt < 2; mt++)
    #pragma unroll
    for (int nt = 0; nt < 2; nt++)
      #pragma unroll
      for (int q = 0; q < 4; q++) {
        int r = rowBase + wr + mt * 16 + kg * 4 + q;
        int c = colBase + wc + nt * 16 + ln15;
        if (c < N) {
          float v = acc[mt][nt][q];
          if (MODE == 1) {
            out[(long)r * N + c] = v + R[(long)r * N + c];
          } else if (MODE == 2) {
            int bb = r >> 7, ch = r & 127;
            out[(long)bb * 131072 + (long)c * 128 + ch] =
                v + R[((long)bb * 1024 + c) * 128 + ch];
          } else {
            if (c < c1) out[(long)r * c1 + c] = v;
            else if (c < c2) o2[(long)r * (c2 - c1) + (c - c1)] = v;
            else o3[(long)r * (N - c2) + (c - c2)] = v;
          }
        }
      }
}

// ---- fused: causal depthwise conv (float4 channels) + bias + SiLU | dt/la ----
// blocks [0, convBlocks): conv part; blocks [convBlocks, ...): dtda part.
__global__ __launch_bounds__(256) void conv_dtda(const float* __restrict__ zx,
                                                 const float* __restrict__ cw,
                                                 const float* __restrict__ cb,
                                                 float* __restrict__ cout,
                                                 const float* __restrict__ raw,
                                                 const float* __restrict__ dtbias,
                                                 const float* __restrict__ alog,
                                                 float* __restrict__ dt,
                                                 float* __restrict__ la,
                                                 int Bb, int L, int conv_dim,
                                                 int H, int rowsH, int convBlocks) {
  int tid = threadIdx.x;
  if ((int)blockIdx.x < convBlocks) {
    long idx4 = (long)blockIdx.x * 256 + tid;
    int nch4 = conv_dim >> 2;
    long total4 = (long)Bb * L * nch4;
    if (idx4 >= total4) return;
    int ch = (int)(idx4 % nch4) << 2;
    long rt = idx4 / nch4;
    int t = (int)(rt % L);
    int b = (int)(rt / L);
    f32x4 acc = *reinterpret_cast<const f32x4*>(&cb[ch]);
    #pragma unroll
    for (int k = 0; k < 4; k++) {
      int tt = t + k - 3;
      if (tt >= 0) {
        f32x4 wv = *reinterpret_cast<const f32x4*>(&cw[k * conv_dim + ch]);
        f32x4 zv = *reinterpret_cast<const f32x4*>(
            &zx[((long)b * L + tt) * conv_dim + ch]);
        acc += wv * zv;
      }
    }
    f32x4 o;
    o[0] = siluf(acc[0]); o[1] = siluf(acc[1]);
    o[2] = siluf(acc[2]); o[3] = siluf(acc[3]);
    *reinterpret_cast<f32x4*>(&cout[rt * conv_dim + ch]) = o;
  } else {
    int idx = ((int)blockIdx.x - convBlocks) * 256 + tid;
    if (idx >= rowsH) return;
    int h = idx % H;
    float v = raw[idx] + dtbias[h];
    float sp = (v > 20.f) ? v : log1pf(expf(v));
    dt[idx] = sp;
    la[idx] = -expf(alog[h]) * sp;
  }
}

// ===================== chunked SSD (T=64 per chunk) =====================
__global__ __launch_bounds__(256) void ssd_local(const float* __restrict__ xbc,
                                                 const float* __restrict__ dtv,
                                                 const float* __restrict__ la,
                                                 float* __restrict__ Sc,
                                                 float* __restrict__ Aprod,
                                                 int NC, int H, int conv_dim,
                                                 int d_inner) {
  int blk = blockIdx.x;
  int c = blk % NC, bh = blk / NC;
  int h = bh % H, b = bh / H;
  int tid = threadIdx.x;
  long row0 = ((long)(b * NC + c)) * 64;
  __shared__ float Xs[64][64];
  __shared__ float Bs[64][64];
  __shared__ float Ws[64];
  int tq = tid >> 4, cq = (tid & 15) << 2;
  #pragma unroll
  for (int i = 0; i < 4; i++) {
    int t = tq + i * 16;
    const float* rp = xbc + (row0 + t) * conv_dim;
    *reinterpret_cast<f32x4*>(&Xs[t][cq]) =
        *reinterpret_cast<const f32x4*>(rp + (h << 6) + cq);
    *reinterpret_cast<f32x4*>(&Bs[t][cq]) =
        *reinterpret_cast<const f32x4*>(rp + d_inner + cq);
  }
  if (tid < 64) {
    long r = (row0 + tid) * H + h;
    float cum = wave_prefix_incl(la[r], tid);
    float cT = __shfl(cum, 63);
    Ws[tid] = expf(cT - cum) * dtv[r];
    if (tid == 63) Aprod[blk] = expf(cT);
  }
  __syncthreads();
  int p0 = (tid >> 4) << 2, n0 = (tid & 15) << 2;
  f32x4 S0 = {0.f, 0.f, 0.f, 0.f}, S1 = S0, S2 = S0, S3 = S0;
  for (int t = 0; t < 64; t++) {
    float w = Ws[t];
    f32x4 xv = *reinterpret_cast<const f32x4*>(&Xs[t][p0]);
    f32x4 bv = *reinterpret_cast<const f32x4*>(&Bs[t][n0]);
    S0 += bv * (w * xv[0]);
    S1 += bv * (w * xv[1]);
    S2 += bv * (w * xv[2]);
    S3 += bv * (w * xv[3]);
  }
  float* base = Sc + (long)blk * 4096;
  *reinterpret_cast<f32x4*>(&base[(p0 + 0) * 64 + n0]) = S0;
  *reinterpret_cast<f32x4*>(&base[(p0 + 1) * 64 + n0]) = S1;
  *reinterpret_cast<f32x4*>(&base[(p0 + 2) * 64 + n0]) = S2;
  *reinterpret_cast<f32x4*>(&base[(p0 + 3) * 64 + n0]) = S3;
}

__global__ __launch_bounds__(256) void ssd_carry(float* __restrict__ Sc,
                                                 const float* __restrict__ Aprod,
                                                 int NC) {
  int bh = blockIdx.x, tid = threadIdx.x;
  int p0 = (tid >> 4) << 2, n0 = (tid & 15) << 2;
  f32x4 h0 = {0.f, 0.f, 0.f, 0.f}, h1 = h0, h2 = h0, h3 = h0;
  for (int c = 0; c < NC; c++) {
    float* base = Sc + ((long)bh * NC + c) * 4096;
    float a = Aprod[bh * NC + c];
    f32x4 s0 = *reinterpret_cast<f32x4*>(&base[(p0 + 0) * 64 + n0]);
    f32x4 s1 = *reinterpret_cast<f32x4*>(&base[(p0 + 1) * 64 + n0]);
    f32x4 s2 = *reinterpret_cast<f32x4*>(&base[(p0 + 2) * 64 + n0]);
    f32x4 s3 = *reinterpret_cast<f32x4*>(&base[(p0 + 3) * 64 + n0]);
    *reinterpret_cast<f32x4*>(&base[(p0 + 0) * 64 + n0]) = h0;
    *reinterpret_cast<f32x4*>(&base[(p0 + 1) * 64 + n0]) = h1;
    *reinterpret_cast<f32x4*>(&base[(p0 + 2) * 64 + n0]) = h2;
    *reinterpret_cast<f32x4*>(&base[(p0 + 3) * 64 + n0]) = h3;
    h0 = h0 * a + s0;
    h1 = h1 * a + s1;
    h2 = h2 * a + s2;
    h3 = h3 * a + s3;
  }
}

__global__ __launch_bounds__(256) void ssd_out(const float* __restrict__ xbc,
                                               const float* __restrict__ dtv,
                                               const float* __restrict__ la,
                                               const float* __restrict__ Hp,
                                               const float* __restrict__ Dvec,
                                               float* __restrict__ y,
                                               int NC, int H, int conv_dim,
                                               int d_inner) {
  int blk = blockIdx.x;
  int c = blk % NC, bh = blk / NC;
  int h = bh % H, b = bh / H;
  int tid = threadIdx.x;
  long row0 = ((long)(b * NC + c)) * 64;
  __shared__ float CsT[64 * 68];   // [n][t]
  __shared__ float shB[64 * 68];   // BsT[n][s]  -> GmT[s][t]
  __shared__ float shX[64 * 68];   // Xs[s][p]   -> HpT[n][p]
  __shared__ float Cum[64], Dt[64];
  int tq = tid >> 4, cq = (tid & 15) << 2;
  #pragma unroll
  for (int i = 0; i < 4; i++) {
    int t = tq + i * 16;
    const float* rp = xbc + (row0 + t) * conv_dim;
    f32x4 cv = *reinterpret_cast<const f32x4*>(rp + d_inner + 64 + cq);
    f32x4 bv = *reinterpret_cast<const f32x4*>(rp + d_inner + cq);
    f32x4 xv = *reinterpret_cast<const f32x4*>(rp + (h << 6) + cq);
    #pragma unroll
    for (int j = 0; j < 4; j++) {
      CsT[(cq + j) * 68 + t] = cv[j];
      shB[(cq + j) * 68 + t] = bv[j];
    }
    *reinterpret_cast<f32x4*>(&shX[t * 68 + cq]) = xv;
  }
  if (tid < 64) {
    long r = (row0 + tid) * H + h;
    Cum[tid] = wave_prefix_incl(la[r], tid);
    Dt[tid] = dtv[r];
  }
  __syncthreads();
  int t0 = (tid >> 4) << 2, q0 = (tid & 15) << 2;
  f32x4 G0 = {0.f, 0.f, 0.f, 0.f}, G1 = G0, G2 = G0, G3 = G0;
  for (int n = 0; n < 64; n++) {
    f32x4 cv = *reinterpret_cast<const f32x4*>(&CsT[n * 68 + t0]);
    f32x4 bv = *reinterpret_cast<const f32x4*>(&shB[n * 68 + q0]);
    G0 += cv * bv[0];
    G1 += cv * bv[1];
    G2 += cv * bv[2];
    G3 += cv * bv[3];
  }
  f32x4 gm[4] = {G0, G1, G2, G3};
  #pragma unroll
  for (int j = 0; j < 4; j++) {
    int s = q0 + j;
    float ds = Dt[s], cs = Cum[s];
    #pragma unroll
    for (int i = 0; i < 4; i++) {
      int t = t0 + i;
      gm[j][i] = (s <= t) ? gm[j][i] * expf(Cum[t] - cs) * ds : 0.f;
    }
  }
  __syncthreads();
  #pragma unroll
  for (int j = 0; j < 4; j++)
    *reinterpret_cast<f32x4*>(&shB[(q0 + j) * 68 + t0]) = gm[j];
  __syncthreads();
  f32x4 Y0 = {0.f, 0.f, 0.f, 0.f}, Y1 = Y0, Y2 = Y0, Y3 = Y0;
  for (int s = 0; s < 64; s++) {
    f32x4 g4 = *reinterpret_cast<const f32x4*>(&shB[s * 68 + t0]);
    f32x4 x4 = *reinterpret_cast<const f32x4*>(&shX[s * 68 + q0]);
    Y0 += x4 * g4[0];
    Y1 += x4 * g4[1];
    Y2 += x4 * g4[2];
    Y3 += x4 * g4[3];
  }
  __syncthreads();
  const float* hb = Hp + (long)blk * 4096;
  #pragma unroll
  for (int i = 0; i < 4; i++) {
    int p = tq + i * 16;
    f32x4 hv = *reinterpret_cast<const f32x4*>(&hb[p * 64 + cq]);
    #pragma unroll
    for (int j = 0; j < 4; j++) shX[(cq + j) * 68 + p] = hv[j];
  }
  __syncthreads();
  f32x4 Z0 = {0.f, 0.f, 0.f, 0.f}, Z1 = Z0, Z2 = Z0, Z3 = Z0;
  for (int n = 0; n < 64; n++) {
    f32x4 cv = *reinterpret_cast<const f32x4*>(&CsT[n * 68 + t0]);
    f32x4 hv = *reinterpret_cast<const f32x4*>(&shX[n * 68 + q0]);
    Z0 += hv * cv[0];
    Z1 += hv * cv[1];
    Z2 += hv * cv[2];
    Z3 += hv * cv[3];
  }
  float Dv = Dvec[h];
  f32x4 Yv[4] = {Y0, Y1, Y2, Y3};
  f32x4 Zv[4] = {Z0, Z1, Z2, Z3};
  #pragma unroll
  for (int i = 0; i < 4; i++) {
    int t = t0 + i;
    float wB = expf(Cum[t]);
    const float* xp = xbc + (row0 + t) * conv_dim + (h << 6) + q0;
    f32x4 xg = *reinterpret_cast<const f32x4*>(xp);
    f32x4 o = Yv[i] + Zv[i] * wB + xg * Dv;
    *reinterpret_cast<f32x4*>(&y[(row0 + t) * d_inner + (h << 6) + q0]) = o;
  }
}

// --- g = y*silu(z); g *= rsqrt(mean(g^2)+eps)*rms_w; emit bf16 A directly ---
template <int NJ>
__global__ __launch_bounds__(256) void gate_rms_bf16(const float* __restrict__ y,
                                                     const float* __restrict__ z,
                                                     const float* __restrict__ rmsw,
                                                     unsigned short* __restrict__ ab,
                                                     int d_inner) {
  long row = blockIdx.x;
  const float* yr = y + row * d_inner;
  const float* zr = z + row * d_inner;
  __shared__ float lds[4];
  float g[NJ];
  float ss = 0.f;
  #pragma unroll
  for (int j = 0; j < NJ; j++) {
    int c = threadIdx.x + (j << 8);
    float gv = yr[c] * siluf(zr[c]);
    g[j] = gv;
    ss += gv * gv;
  }
  float tot = block_sum(ss, lds);
  float inv = rsqrtf(tot / (float)d_inner + EPSV);
  #pragma unroll
  for (int j = 0; j < NJ; j++) {
    int c = threadIdx.x + (j << 8);
    ab[row * d_inner + c] = f2bf(g[j] * inv * rmsw[c]);
  }
}

extern "C" void kernel_launch(void* const* d_in, const int* in_sizes, int n_in,
                              void* d_out, int out_size, void* d_ws,
                              size_t ws_size, hipStream_t stream) {
  const float* x        = (const float*)d_in[0];
  const float* ln_spa_w = (const float*)d_in[1];
  const float* ln_spa_b = (const float*)d_in[2];
  const float* ln_spe_w = (const float*)d_in[3];
  const float* ln_spe_b = (const float*)d_in[4];
  const float* spa_W_in   = (const float*)d_in[5];
  const float* spa_conv_w = (const float*)d_in[6];
  const float* spa_conv_b = (const float*)d_in[7];
  const float* spa_dt_b   = (const float*)d_in[8];
  const float* spa_A_log  = (const float*)d_in[9];
  const float* spa_D      = (const float*)d_in[10];
  const float* spa_rms_w  = (const float*)d_in[11];
  const float* spa_W_out  = (const float*)d_in[12];
  const float* spe_W_in   = (const float*)d_in[13];
  const float* spe_conv_w = (const float*)d_in[14];
  const float* spe_conv_b = (const float*)d_in[15];
  const float* spe_dt_b   = (const float*)d_in[16];
  const float* spe_A_log  = (const float*)d_in[17];
  const float* spe_D      = (const float*)d_in[18];
  const float* spe_rms_w  = (const float*)d_in[19];
  const float* spe_W_out  = (const float*)d_in[20];
  float* out = (float*)d_out;

  float* ws = (float*)d_ws;
  // layout (floats), total 15,968,512 = 63.9 MB
  float* xspa   = ws;                 // 1,048,576
  float* z      = ws + 1048576;       // 2,097,152
  float* xbcraw = ws + 3145728;       // 3,145,728 (later Sc)
  float* dtraw  = ws + 6291456;       // 32,768    (later Aprod)
  float* cv     = ws + 6324224;       // 3,145,728
  float* dtb    = ws + 9469952;       // 32,768
  float* la     = ws + 9502720;       // 32,768
  float* yb     = ws + 9535488;       // 2,097,152
  float* stats  = ws + 11632640;      // 2,048
  unsigned short* Abf     = (unsigned short*)(ws + 11634688);  // 1,048,576 fl
  unsigned short* Wt_spai = (unsigned short*)(ws + 12683264);  // 41,216 fl
  unsigned short* Wt_spao = (unsigned short*)(ws + 12724480);  // 16,384 fl
  unsigned short* Wt_spei = (unsigned short*)(ws + 12740864);  // 2,179,072 fl
  unsigned short* Wt_speo = (unsigned short*)(ws + 14919936);  // 1,048,576 fl

  // 1. all weight transposes (independent of everything)
  hipLaunchKernelGGL(wtconv_all, dim3(1614), dim3(256), 0, stream,
                     spa_W_in, Wt_spai, spa_W_out, Wt_spao,
                     spe_W_in, Wt_spei, spe_W_out, Wt_speo);

  // ================= spatial mamba (L=1024, d_model=128) =================
  hipLaunchKernelGGL(ln_rows128_bf16, dim3(8192), dim3(256), 0, stream,
                     x, ln_spa_w, ln_spa_b, Abf);
  hipLaunchKernelGGL((gemm_mfma<3>), dim3(11, 128), dim3(256), 0, stream,
                     Abf, Wt_spai, nullptr, z, xbcraw, dtraw,
                     8192, 644, 128, 256, 640);
  hipLaunchKernelGGL(conv_dtda, dim3(3200), dim3(256), 0, stream,
                     xbcraw, spa_conv_w, spa_conv_b, cv,
                     dtraw, spa_dt_b, spa_A_log, dtb, la,
                     8, 1024, 384, 4, 32768, 3072);
  hipLaunchKernelGGL(ssd_local, dim3(512), dim3(256), 0, stream,
                     cv, dtb, la, xbcraw, dtraw, 16, 4, 384, 256);
  hipLaunchKernelGGL(ssd_carry, dim3(32), dim3(256), 0, stream,
                     xbcraw, dtraw, 16);
  hipLaunchKernelGGL(ssd_out, dim3(512), dim3(256), 0, stream,
                     cv, dtb, la, xbcraw, spa_D, yb, 16, 4, 384, 256);
  hipLaunchKernelGGL((gate_rms_bf16<1>), dim3(8192), dim3(256), 0, stream,
                     yb, z, spa_rms_w, Abf, 256);
  hipLaunchKernelGGL((gemm_mfma<1>), dim3(2, 128), dim3(256), 0, stream,
                     Abf, Wt_spao, x, xspa, nullptr, nullptr,
                     8192, 128, 256, 0, 0);

  // ================= spectral mamba (L=128, d_model=1024) =================
  hipLaunchKernelGGL(spe_stats, dim3(8), dim3(256), 0, stream, xspa, stats);
  hipLaunchKernelGGL(spe_normT, dim3(2, 8, 8), dim3(256), 0, stream,
                     xspa, stats, ln_spe_w, ln_spe_b, Abf);
  hipLaunchKernelGGL((gemm_mfma<3>), dim3(67, 16), dim3(256), 0, stream,
                     Abf, Wt_spei, nullptr, z, xbcraw, dtraw,
                     1024, 4256, 1024, 2048, 4224);
  hipLaunchKernelGGL(conv_dtda, dim3(2304), dim3(256), 0, stream,
                     xbcraw, spe_conv_w, spe_conv_b, cv,
                     dtraw, spe_dt_b, spe_A_log, dtb, la,
                     8, 128, 2176, 32, 32768, 2176);
  hipLaunchKernelGGL(ssd_local, dim3(512), dim3(256), 0, stream,
                     cv, dtb, la, xbcraw, dtraw, 2, 32, 2176, 2048);
  hipLaunchKernelGGL(ssd_carry, dim3(256), dim3(256), 0, stream,
                     xbcraw, dtraw, 2);
  hipLaunchKernelGGL(ssd_out, dim3(512), dim3(256), 0, stream,
                     cv, dtb, la, xbcraw, spe_D, yb, 2, 32, 2176, 2048);
  hipLaunchKernelGGL((gate_rms_bf16<8>), dim3(1024), dim3(256), 0, stream,
                     yb, z, spe_rms_w, Abf, 2048);
  hipLaunchKernelGGL((gemm_mfma<2>), dim3(16, 16), dim3(256), 0, stream,
                     Abf, Wt_speo, xspa, out, nullptr, nullptr,
                     1024, 1024, 2048, 0, 0);
}

// Round 7
// 211.467 us; speedup vs baseline: 4.9076x; 1.0555x over previous
//
#include <hip/hip_runtime.h>
#include <hip/hip_bf16.h>

#define EPSV 1e-5f

typedef __attribute__((ext_vector_type(8))) short short8v;   // 8 bf16 in 4 VGPRs
typedef __attribute__((ext_vector_type(4))) float f32x4;

__device__ inline unsigned short f2bf(float f) {
  __hip_bfloat16 h = __float2bfloat16(f);
  return *reinterpret_cast<unsigned short*>(&h);
}

// ---------------- block-wide sum (256 threads = 4 waves) ----------------
__device__ inline float block_sum(float v, float* lds) {
  #pragma unroll
  for (int o = 32; o; o >>= 1) v += __shfl_xor(v, o);
  int tid = threadIdx.x;
  if ((tid & 63) == 0) lds[tid >> 6] = v;
  __syncthreads();
  float r = lds[0] + lds[1] + lds[2] + lds[3];
  __syncthreads();
  return r;
}

__device__ inline float siluf(float x) { return x / (1.f + expf(-x)); }

// inclusive prefix sum over 64 lanes (call from wave 0 only)
__device__ inline float wave_prefix_incl(float v, int lane) {
  #pragma unroll
  for (int o = 1; o < 64; o <<= 1) {
    float u = __shfl_up(v, o);
    if (lane >= o) v += u;
  }
  return v;
}

// ---- LayerNorm rows of 128, 128 threads/block (all lanes active), bf16 out ----
__global__ __launch_bounds__(128) void ln_rows128_bf16(const float* __restrict__ x,
                                                       const float* __restrict__ w,
                                                       const float* __restrict__ bb,
                                                       unsigned short* __restrict__ out) {
  long row = blockIdx.x;
  int tid = threadIdx.x;
  __shared__ float lds[2];
  float v = x[row * 128 + tid];
  float s = v;
  #pragma unroll
  for (int o = 32; o; o >>= 1) s += __shfl_xor(s, o);
  if ((tid & 63) == 0) lds[tid >> 6] = s;
  __syncthreads();
  float m = (lds[0] + lds[1]) * (1.f / 128.f);
  float d = v - m;
  float q = d * d;
  #pragma unroll
  for (int o = 32; o; o >>= 1) q += __shfl_xor(q, o);
  __syncthreads();
  if ((tid & 63) == 0) lds[tid >> 6] = q;
  __syncthreads();
  float inv = rsqrtf((lds[0] + lds[1]) * (1.f / 128.f) + EPSV);
  out[row * 128 + tid] = f2bf(d * inv * w[tid] + bb[tid]);
}

// ---- spe LN pass 1: partial sums over 256-row L-segments (grid: seg×b) ----
// part[((seg*8 + b)*128 + ch)*2] = {sum, sumsq}
__global__ __launch_bounds__(256) void spe_stats_part(const float* __restrict__ xspa,
                                                      float* __restrict__ part) {
  int seg = blockIdx.x, b = blockIdx.y;
  int tid = threadIdx.x;
  int sub = tid >> 5;          // 8 sub-segments of 32 rows
  int cg = (tid & 31) * 4;
  const float* base = xspa + (long)b * 131072 + (long)(seg * 256 + sub * 32) * 128 + cg;
  f32x4 s = {0.f, 0.f, 0.f, 0.f}, q = s;
  for (int l = 0; l < 32; l++) {
    f32x4 v = *reinterpret_cast<const f32x4*>(base + l * 128);
    s += v;
    q += v * v;
  }
  __shared__ float S[8][128], Q[8][128];
  *reinterpret_cast<f32x4*>(&S[sub][cg]) = s;
  *reinterpret_cast<f32x4*>(&Q[sub][cg]) = q;
  __syncthreads();
  if (tid < 128) {
    float ss = 0.f, qq = 0.f;
    #pragma unroll
    for (int i = 0; i < 8; i++) { ss += S[i][tid]; qq += Q[i][tid]; }
    float2 o; o.x = ss; o.y = qq;
    *reinterpret_cast<float2*>(&part[((seg * 8 + b) * 128 + tid) * 2]) = o;
  }
}

// ---- spe LN pass 2: finalize stats + normalize + transpose, emit bf16 ----
// grid: (2 ch-tiles of 64, 8 l-tiles of 128, 8 b)
__global__ __launch_bounds__(256) void spe_normT(const float* __restrict__ xspa,
                                                 const float* __restrict__ part,
                                                 const float* __restrict__ w,
                                                 const float* __restrict__ bb,
                                                 unsigned short* __restrict__ out) {
  __shared__ float tile[128][65];
  int c0 = blockIdx.x * 64, l0 = blockIdx.y * 128, b = blockIdx.z;
  int tid = threadIdx.x;
  int rr = tid >> 4, c4 = (tid & 15) * 4;
  #pragma unroll
  for (int p = 0; p < 8; p++) {
    int l = rr + p * 16;
    f32x4 v = *reinterpret_cast<const f32x4*>(
        &xspa[((long)b * 1024 + l0 + l) * 128 + c0 + c4]);
    tile[l][c4] = v[0]; tile[l][c4 + 1] = v[1];
    tile[l][c4 + 2] = v[2]; tile[l][c4 + 3] = v[3];
  }
  __syncthreads();
  int ch = tid >> 2, lq = tid & 3;
  float ssum = 0.f, qsum = 0.f;
  #pragma unroll
  for (int sgi = 0; sgi < 4; sgi++) {
    float2 pq = *reinterpret_cast<const float2*>(&part[((sgi * 8 + b) * 128 + c0 + ch) * 2]);
    ssum += pq.x; qsum += pq.y;
  }
  float mm = ssum * (1.f / 1024.f);
  float rstd = rsqrtf(qsum * (1.f / 1024.f) - mm * mm + EPSV);
  #pragma unroll
  for (int j = 0; j < 8; j++) {
    int qidx = lq + j * 4;
    int l = qidx * 4;
    float4 wv = *reinterpret_cast<const float4*>(&w[l0 + l]);
    float4 bv = *reinterpret_cast<const float4*>(&bb[l0 + l]);
    ushort4 o;
    o.x = f2bf((tile[l + 0][ch] - mm) * rstd * wv.x + bv.x);
    o.y = f2bf((tile[l + 1][ch] - mm) * rstd * wv.y + bv.y);
    o.z = f2bf((tile[l + 2][ch] - mm) * rstd * wv.z + bv.z);
    o.w = f2bf((tile[l + 3][ch] - mm) * rstd * wv.w + bv.w);
    *reinterpret_cast<ushort4*>(&out[((long)b * 128 + c0 + ch) * 1024 + l0 + l]) = o;
  }
}

// ------- all 4 weight transposes W[K][N] -> Wt[N][K] bf16, one launch -------
__device__ inline void wtconv_tile(const float* __restrict__ W,
                                   unsigned short* __restrict__ Wt,
                                   int K, int N, int bx, int by) {
  __shared__ float tile[64][65];
  int n0 = bx * 64, k0 = by * 64;
  int tid = threadIdx.x;
  int r = tid >> 4, c4 = (tid & 15) * 4;
  #pragma unroll
  for (int i = 0; i < 4; i++) {
    int kk = r + i * 16;
    float4 v = make_float4(0.f, 0.f, 0.f, 0.f);
    if (n0 + c4 < N) v = *reinterpret_cast<const float4*>(&W[(long)(k0 + kk) * N + n0 + c4]);
    tile[kk][c4] = v.x; tile[kk][c4 + 1] = v.y; tile[kk][c4 + 2] = v.z; tile[kk][c4 + 3] = v.w;
  }
  __syncthreads();
  #pragma unroll
  for (int i = 0; i < 4; i++) {
    int nl = r + i * 16;
    if (n0 + nl < N) {
      ushort4 o;
      o.x = f2bf(tile[c4 + 0][nl]);
      o.y = f2bf(tile[c4 + 1][nl]);
      o.z = f2bf(tile[c4 + 2][nl]);
      o.w = f2bf(tile[c4 + 3][nl]);
      *reinterpret_cast<ushort4*>(&Wt[(long)(n0 + nl) * K + k0 + c4]) = o;
    }
  }
}

__global__ __launch_bounds__(256) void wtconv_all(const float* __restrict__ W0,
                                                  unsigned short* __restrict__ T0,
                                                  const float* __restrict__ W1,
                                                  unsigned short* __restrict__ T1,
                                                  const float* __restrict__ W2,
                                                  unsigned short* __restrict__ T2,
                                                  const float* __restrict__ W3,
                                                  unsigned short* __restrict__ T3) {
  int id = blockIdx.x;
  if (id < 22)        { int r = id;        wtconv_tile(W0, T0, 128,  644,  r % 11, r / 11); }
  else if (id < 30)   { int r = id - 22;   wtconv_tile(W1, T1, 256,  128,  r % 2,  r / 2); }
  else if (id < 1102) { int r = id - 30;   wtconv_tile(W2, T2, 1024, 4256, r % 67, r / 67); }
  else                { int r = id - 1102; wtconv_tile(W3, T3, 2048, 1024, r % 16, r / 16); }
}

// ------- 128x128-tile bf16 MFMA GEMM with column-split epilogue -------
// out gets cols [0,c1), o2 [c1,c2), o3 [c2,N). M%128==0, K%32==0; N guarded.
__global__ __launch_bounds__(256) void gemm128_split(const unsigned short* __restrict__ A,
                                                     const unsigned short* __restrict__ Bt,
                                                     float* __restrict__ out,
                                                     float* __restrict__ o2,
                                                     float* __restrict__ o3,
                                                     int M, int N, int K,
                                                     int c1, int c2) {
  __shared__ unsigned short As[128 * 40];
  __shared__ unsigned short Bs[128 * 40];
  int tid = threadIdx.x;
  int lane = tid & 63, w = tid >> 6;
  int wr = (w >> 1) * 64, wc = (w & 1) * 64;
  int ln15 = lane & 15, kg = lane >> 4;
  int rowBase = blockIdx.y * 128, colBase = blockIdx.x * 128;
  int sr = tid >> 1, sk = (tid & 1) * 16;
  f32x4 acc[4][4] = {};
  for (int k0 = 0; k0 < K; k0 += 32) {
    {
      const unsigned short* ap = &A[(long)(rowBase + sr) * K + k0 + sk];
      short8v a0 = *reinterpret_cast<const short8v*>(ap);
      short8v a1 = *reinterpret_cast<const short8v*>(ap + 8);
      *reinterpret_cast<short8v*>(&As[sr * 40 + sk]) = a0;
      *reinterpret_cast<short8v*>(&As[sr * 40 + sk + 8]) = a1;
      int n = colBase + sr;
      short8v b0 = {0, 0, 0, 0, 0, 0, 0, 0}, b1 = b0;
      if (n < N) {
        const unsigned short* bp = &Bt[(long)n * K + k0 + sk];
        b0 = *reinterpret_cast<const short8v*>(bp);
        b1 = *reinterpret_cast<const short8v*>(bp + 8);
      }
      *reinterpret_cast<short8v*>(&Bs[sr * 40 + sk]) = b0;
      *reinterpret_cast<short8v*>(&Bs[sr * 40 + sk + 8]) = b1;
    }
    __syncthreads();
    short8v af[4], bfr[4];
    #pragma unroll
    for (int mt = 0; mt < 4; mt++)
      af[mt] = *reinterpret_cast<const short8v*>(&As[(wr + mt * 16 + ln15) * 40 + kg * 8]);
    #pragma unroll
    for (int nt = 0; nt < 4; nt++)
      bfr[nt] = *reinterpret_cast<const short8v*>(&Bs[(wc + nt * 16 + ln15) * 40 + kg * 8]);
    #pragma unroll
    for (int mt = 0; mt < 4; mt++)
      #pragma unroll
      for (int nt = 0; nt < 4; nt++)
        acc[mt][nt] = __builtin_amdgcn_mfma_f32_16x16x32_bf16(af[mt], bfr[nt], acc[mt][nt], 0, 0, 0);
    __syncthreads();
  }
  #pragma unroll
  for (int mt = 0; mt < 4; mt++)
    #pragma unroll
    for (int nt = 0; nt < 4; nt++)
      #pragma unroll
      for (int q = 0; q < 4; q++) {
        int r = rowBase + wr + mt * 16 + kg * 4 + q;
        int c = colBase + wc + nt * 16 + ln15;
        if (c < N) {
          float v = acc[mt][nt][q];
          if (c < c1) out[(long)r * c1 + c] = v;
          else if (c < c2) o2[(long)r * (c2 - c1) + (c - c1)] = v;
          else o3[(long)r * (N - c2) + (c - c2)] = v;
        }
      }
}

// ---------------- 64x64-tile bf16 MFMA GEMM (W_out epilogues) ----------------
// MODE 1: out = v + R (same layout).
// MODE 2: transposed add (spe W_out): r=(b,ch) b=r>>7 ch=r&127;
//         out[b][c][ch] = v + R[b][c][ch].
template <int MODE>
__global__ __launch_bounds__(256) void gemm_mfma(const unsigned short* __restrict__ A,
                                                 const unsigned short* __restrict__ Bt,
                                                 const float* __restrict__ R,
                                                 float* __restrict__ out,
                                                 int M, int N, int K) {
  __shared__ unsigned short As[64 * 40];
  __shared__ unsigned short Bs[64 * 40];
  int tid = threadIdx.x;
  int lane = tid & 63, w = tid >> 6;
  int wr = (w >> 1) * 32, wc = (w & 1) * 32;
  int ln15 = lane & 15, kg = lane >> 4;
  int rowBase = blockIdx.y * 64, colBase = blockIdx.x * 64;
  int sm = tid >> 2, skb = (tid & 3) * 8;
  f32x4 acc[2][2] = {};
  for (int k0 = 0; k0 < K; k0 += 32) {
    {
      short8v av = *reinterpret_cast<const short8v*>(&A[(long)(rowBase + sm) * K + k0 + skb]);
      *reinterpret_cast<short8v*>(&As[sm * 40 + skb]) = av;
      int n = colBase + sm;
      short8v bv = {0, 0, 0, 0, 0, 0, 0, 0};
      if (n < N) bv = *reinterpret_cast<const short8v*>(&Bt[(long)n * K + k0 + skb]);
      *reinterpret_cast<short8v*>(&Bs[sm * 40 + skb]) = bv;
    }
    __syncthreads();
    short8v af[2], bfr[2];
    #pragma unroll
    for (int mt = 0; mt < 2; mt++)
      af[mt] = *reinterpret_cast<const short8v*>(&As[(wr + mt * 16 + ln15) * 40 + kg * 8]);
    #pragma unroll
    for (int nt = 0; nt < 2; nt++)
      bfr[nt] = *reinterpret_cast<const short8v*>(&Bs[(wc + nt * 16 + ln15) * 40 + kg * 8]);
    #pragma unroll
    for (int mt = 0; mt < 2; mt++)
      #pragma unroll
      for (int nt = 0; nt < 2; nt++)
        acc[mt][nt] = __builtin_amdgcn_mfma_f32_16x16x32_bf16(af[mt], bfr[nt], acc[mt][nt], 0, 0, 0);
    __syncthreads();
  }
  #pragma unroll
  for (int mt = 0; mt < 2; mt++)
    #pragma unroll
    for (int nt = 0; nt < 2; nt++)
      #pragma unroll
      for (int q = 0; q < 4; q++) {
        int r = rowBase + wr + mt * 16 + kg * 4 + q;
        int c = colBase + wc + nt * 16 + ln15;
        if (c < N) {
          float v = acc[mt][nt][q];
          if (MODE == 1) {
            out[(long)r * N + c] = v + R[(long)r * N + c];
          } else {
            int bb = r >> 7, ch = r & 127;
            out[(long)bb * 131072 + (long)c * 128 + ch] =
                v + R[((long)bb * 1024 + c) * 128 + ch];
          }
        }
      }
}

// ---- fused: causal depthwise conv (float4 channels) + bias + SiLU | dt/la ----
__global__ __launch_bounds__(256) void conv_dtda(const float* __restrict__ zx,
                                                 const float* __restrict__ cw,
                                                 const float* __restrict__ cb,
                                                 float* __restrict__ cout,
                                                 const float* __restrict__ raw,
                                                 const float* __restrict__ dtbias,
                                                 const float* __restrict__ alog,
                                                 float* __restrict__ dt,
                                                 float* __restrict__ la,
                                                 int Bb, int L, int conv_dim,
                                                 int H, int rowsH, int convBlocks) {
  int tid = threadIdx.x;
  if ((int)blockIdx.x < convBlocks) {
    long idx4 = (long)blockIdx.x * 256 + tid;
    int nch4 = conv_dim >> 2;
    long total4 = (long)Bb * L * nch4;
    if (idx4 >= total4) return;
    int ch = (int)(idx4 % nch4) << 2;
    long rt = idx4 / nch4;
    int t = (int)(rt % L);
    int b = (int)(rt / L);
    f32x4 acc = *reinterpret_cast<const f32x4*>(&cb[ch]);
    #pragma unroll
    for (int k = 0; k < 4; k++) {
      int tt = t + k - 3;
      if (tt >= 0) {
        f32x4 wv = *reinterpret_cast<const f32x4*>(&cw[k * conv_dim + ch]);
        f32x4 zv = *reinterpret_cast<const f32x4*>(
            &zx[((long)b * L + tt) * conv_dim + ch]);
        acc += wv * zv;
      }
    }
    f32x4 o;
    o[0] = siluf(acc[0]); o[1] = siluf(acc[1]);
    o[2] = siluf(acc[2]); o[3] = siluf(acc[3]);
    *reinterpret_cast<f32x4*>(&cout[rt * conv_dim + ch]) = o;
  } else {
    int idx = ((int)blockIdx.x - convBlocks) * 256 + tid;
    if (idx >= rowsH) return;
    int h = idx % H;
    float v = raw[idx] + dtbias[h];
    float sp = (v > 20.f) ? v : log1pf(expf(v));
    dt[idx] = sp;
    la[idx] = -expf(alog[h]) * sp;
  }
}

// ===================== chunked SSD (T=64 per chunk) =====================
__global__ __launch_bounds__(256) void ssd_local(const float* __restrict__ xbc,
                                                 const float* __restrict__ dtv,
                                                 const float* __restrict__ la,
                                                 float* __restrict__ Sc,
                                                 float* __restrict__ Aprod,
                                                 int NC, int H, int conv_dim,
                                                 int d_inner) {
  int blk = blockIdx.x;
  int c = blk % NC, bh = blk / NC;
  int h = bh % H, b = bh / H;
  int tid = threadIdx.x;
  long row0 = ((long)(b * NC + c)) * 64;
  __shared__ float Xs[64][64];
  __shared__ float Bs[64][64];
  __shared__ float Ws[64];
  int tq = tid >> 4, cq = (tid & 15) << 2;
  #pragma unroll
  for (int i = 0; i < 4; i++) {
    int t = tq + i * 16;
    const float* rp = xbc + (row0 + t) * conv_dim;
    *reinterpret_cast<f32x4*>(&Xs[t][cq]) =
        *reinterpret_cast<const f32x4*>(rp + (h << 6) + cq);
    *reinterpret_cast<f32x4*>(&Bs[t][cq]) =
        *reinterpret_cast<const f32x4*>(rp + d_inner + cq);
  }
  if (tid < 64) {
    long r = (row0 + tid) * H + h;
    float cum = wave_prefix_incl(la[r], tid);
    float cT = __shfl(cum, 63);
    Ws[tid] = expf(cT - cum) * dtv[r];
    if (tid == 63) Aprod[blk] = expf(cT);
  }
  __syncthreads();
  int p0 = (tid >> 4) << 2, n0 = (tid & 15) << 2;
  f32x4 S0 = {0.f, 0.f, 0.f, 0.f}, S1 = S0, S2 = S0, S3 = S0;
  for (int t = 0; t < 64; t++) {
    float w = Ws[t];
    f32x4 xv = *reinterpret_cast<const f32x4*>(&Xs[t][p0]);
    f32x4 bv = *reinterpret_cast<const f32x4*>(&Bs[t][n0]);
    S0 += bv * (w * xv[0]);
    S1 += bv * (w * xv[1]);
    S2 += bv * (w * xv[2]);
    S3 += bv * (w * xv[3]);
  }
  float* base = Sc + (long)blk * 4096;
  *reinterpret_cast<f32x4*>(&base[(p0 + 0) * 64 + n0]) = S0;
  *reinterpret_cast<f32x4*>(&base[(p0 + 1) * 64 + n0]) = S1;
  *reinterpret_cast<f32x4*>(&base[(p0 + 2) * 64 + n0]) = S2;
  *reinterpret_cast<f32x4*>(&base[(p0 + 3) * 64 + n0]) = S3;
}

// carry parallelized over p: grid = BH * 8 blocks, 128 threads, 8 p-rows each
__global__ __launch_bounds__(128) void ssd_carry(float* __restrict__ Sc,
                                                 const float* __restrict__ Aprod,
                                                 int NC) {
  int blk = blockIdx.x;
  int bh = blk >> 3, ps = blk & 7;
  int tid = threadIdx.x;
  int p = ps * 8 + (tid >> 4);
  int n0 = (tid & 15) << 2;
  long off = (long)p * 64 + n0;
  f32x4 hacc = {0.f, 0.f, 0.f, 0.f};
  for (int c = 0; c < NC; c++) {
    float* base = Sc + ((long)bh * NC + c) * 4096;
    float a = Aprod[bh * NC + c];
    f32x4 s = *reinterpret_cast<f32x4*>(&base[off]);
    *reinterpret_cast<f32x4*>(&base[off]) = hacc;
    hacc = hacc * a + s;
  }
}

__global__ __launch_bounds__(256) void ssd_out(const float* __restrict__ xbc,
                                               const float* __restrict__ dtv,
                                               const float* __restrict__ la,
                                               const float* __restrict__ Hp,
                                               const float* __restrict__ Dvec,
                                               float* __restrict__ y,
                                               int NC, int H, int conv_dim,
                                               int d_inner) {
  int blk = blockIdx.x;
  int c = blk % NC, bh = blk / NC;
  int h = bh % H, b = bh / H;
  int tid = threadIdx.x;
  long row0 = ((long)(b * NC + c)) * 64;
  __shared__ float CsT[64 * 68];   // [n][t]
  __shared__ float shB[64 * 68];   // BsT[n][s]  -> GmT[s][t]
  __shared__ float shX[64 * 68];   // Xs[s][p]   -> HpT[n][p]
  __shared__ float Cum[64], Dt[64];
  int tq = tid >> 4, cq = (tid & 15) << 2;
  #pragma unroll
  for (int i = 0; i < 4; i++) {
    int t = tq + i * 16;
    const float* rp = xbc + (row0 + t) * conv_dim;
    f32x4 cv = *reinterpret_cast<const f32x4*>(rp + d_inner + 64 + cq);
    f32x4 bv = *reinterpret_cast<const f32x4*>(rp + d_inner + cq);
    f32x4 xv = *reinterpret_cast<const f32x4*>(rp + (h << 6) + cq);
    #pragma unroll
    for (int j = 0; j < 4; j++) {
      CsT[(cq + j) * 68 + t] = cv[j];
      shB[(cq + j) * 68 + t] = bv[j];
    }
    *reinterpret_cast<f32x4*>(&shX[t * 68 + cq]) = xv;
  }
  if (tid < 64) {
    long r = (row0 + tid) * H + h;
    Cum[tid] = wave_prefix_incl(la[r], tid);
    Dt[tid] = dtv[r];
  }
  __syncthreads();
  int t0 = (tid >> 4) << 2, q0 = (tid & 15) << 2;
  f32x4 G0 = {0.f, 0.f, 0.f, 0.f}, G1 = G0, G2 = G0, G3 = G0;
  for (int n = 0; n < 64; n++) {
    f32x4 cv = *reinterpret_cast<const f32x4*>(&CsT[n * 68 + t0]);
    f32x4 bv = *reinterpret_cast<const f32x4*>(&shB[n * 68 + q0]);
    G0 += cv * bv[0];
    G1 += cv * bv[1];
    G2 += cv * bv[2];
    G3 += cv * bv[3];
  }
  f32x4 gm[4] = {G0, G1, G2, G3};
  #pragma unroll
  for (int j = 0; j < 4; j++) {
    int s = q0 + j;
    float ds = Dt[s], cs = Cum[s];
    #pragma unroll
    for (int i = 0; i < 4; i++) {
      int t = t0 + i;
      gm[j][i] = (s <= t) ? gm[j][i] * expf(Cum[t] - cs) * ds : 0.f;
    }
  }
  __syncthreads();
  #pragma unroll
  for (int j = 0; j < 4; j++)
    *reinterpret_cast<f32x4*>(&shB[(q0 + j) * 68 + t0]) = gm[j];
  __syncthreads();
  f32x4 Y0 = {0.f, 0.f, 0.f, 0.f}, Y1 = Y0, Y2 = Y0, Y3 = Y0;
  for (int s = 0; s < 64; s++) {
    f32x4 g4 = *reinterpret_cast<const f32x4*>(&shB[s * 68 + t0]);
    f32x4 x4 = *reinterpret_cast<const f32x4*>(&shX[s * 68 + q0]);
    Y0 += x4 * g4[0];
    Y1 += x4 * g4[1];
    Y2 += x4 * g4[2];
    Y3 += x4 * g4[3];
  }
  __syncthreads();
  const float* hb = Hp + (long)blk * 4096;
  #pragma unroll
  for (int i = 0; i < 4; i++) {
    int p = tq + i * 16;
    f32x4 hv = *reinterpret_cast<const f32x4*>(&hb[p * 64 + cq]);
    #pragma unroll
    for (int j = 0; j < 4; j++) shX[(cq + j) * 68 + p] = hv[j];
  }
  __syncthreads();
  f32x4 Z0 = {0.f, 0.f, 0.f, 0.f}, Z1 = Z0, Z2 = Z0, Z3 = Z0;
  for (int n = 0; n < 64; n++) {
    f32x4 cv = *reinterpret_cast<const f32x4*>(&CsT[n * 68 + t0]);
    f32x4 hv = *reinterpret_cast<const f32x4*>(&shX[n * 68 + q0]);
    Z0 += hv * cv[0];
    Z1 += hv * cv[1];
    Z2 += hv * cv[2];
    Z3 += hv * cv[3];
  }
  float Dv = Dvec[h];
  f32x4 Yv[4] = {Y0, Y1, Y2, Y3};
  f32x4 Zv[4] = {Z0, Z1, Z2, Z3};
  #pragma unroll
  for (int i = 0; i < 4; i++) {
    int t = t0 + i;
    float wB = expf(Cum[t]);
    const float* xp = xbc + (row0 + t) * conv_dim + (h << 6) + q0;
    f32x4 xg = *reinterpret_cast<const f32x4*>(xp);
    f32x4 o = Yv[i] + Zv[i] * wB + xg * Dv;
    *reinterpret_cast<f32x4*>(&y[(row0 + t) * d_inner + (h << 6) + q0]) = o;
  }
}

// --- g = y*silu(z); g *= rsqrt(mean(g^2)+eps)*rms_w; emit bf16 A directly ---
template <int NJ>
__global__ __launch_bounds__(256) void gate_rms_bf16(const float* __restrict__ y,
                                                     const float* __restrict__ z,
                                                     const float* __restrict__ rmsw,
                                                     unsigned short* __restrict__ ab,
                                                     int d_inner) {
  long row = blockIdx.x;
  const float* yr = y + row * d_inner;
  const float* zr = z + row * d_inner;
  __shared__ float lds[4];
  float g[NJ];
  float ss = 0.f;
  #pragma unroll
  for (int j = 0; j < NJ; j++) {
    int c = threadIdx.x + (j << 8);
    float gv = yr[c] * siluf(zr[c]);
    g[j] = gv;
    ss += gv * gv;
  }
  float tot = block_sum(ss, lds);
  float inv = rsqrtf(tot / (float)d_inner + EPSV);
  #pragma unroll
  for (int j = 0; j < NJ; j++) {
    int c = threadIdx.x + (j << 8);
    ab[row * d_inner + c] = f2bf(g[j] * inv * rmsw[c]);
  }
}

extern "C" void kernel_launch(void* const* d_in, const int* in_sizes, int n_in,
                              void* d_out, int out_size, void* d_ws,
                              size_t ws_size, hipStream_t stream) {
  const float* x        = (const float*)d_in[0];
  const float* ln_spa_w = (const float*)d_in[1];
  const float* ln_spa_b = (const float*)d_in[2];
  const float* ln_spe_w = (const float*)d_in[3];
  const float* ln_spe_b = (const float*)d_in[4];
  const float* spa_W_in   = (const float*)d_in[5];
  const float* spa_conv_w = (const float*)d_in[6];
  const float* spa_conv_b = (const float*)d_in[7];
  const float* spa_dt_b   = (const float*)d_in[8];
  const float* spa_A_log  = (const float*)d_in[9];
  const float* spa_D      = (const float*)d_in[10];
  const float* spa_rms_w  = (const float*)d_in[11];
  const float* spa_W_out  = (const float*)d_in[12];
  const float* spe_W_in   = (const float*)d_in[13];
  const float* spe_conv_w = (const float*)d_in[14];
  const float* spe_conv_b = (const float*)d_in[15];
  const float* spe_dt_b   = (const float*)d_in[16];
  const float* spe_A_log  = (const float*)d_in[17];
  const float* spe_D      = (const float*)d_in[18];
  const float* spe_rms_w  = (const float*)d_in[19];
  const float* spe_W_out  = (const float*)d_in[20];
  float* out = (float*)d_out;

  float* ws = (float*)d_ws;
  // layout (floats), total 15,968,512 = 63.9 MB
  float* xspa   = ws;                 // 1,048,576
  float* z      = ws + 1048576;       // 2,097,152
  float* xbcraw = ws + 3145728;       // 3,145,728 (later Sc)
  float* dtraw  = ws + 6291456;       // 32,768    (later Aprod)
  float* cv     = ws + 6324224;       // 3,145,728
  float* dtb    = ws + 9469952;       // 32,768    (also spe LN partials)
  float* la     = ws + 9502720;       // 32,768
  float* yb     = ws + 9535488;       // 2,097,152
  unsigned short* Abf     = (unsigned short*)(ws + 11634688);  // 1,048,576 fl
  unsigned short* Wt_spai = (unsigned short*)(ws + 12683264);  // 41,216 fl
  unsigned short* Wt_spao = (unsigned short*)(ws + 12724480);  // 16,384 fl
  unsigned short* Wt_spei = (unsigned short*)(ws + 12740864);  // 2,179,072 fl
  unsigned short* Wt_speo = (unsigned short*)(ws + 14919936);  // 1,048,576 fl

  // 1. all weight transposes (independent of everything)
  hipLaunchKernelGGL(wtconv_all, dim3(1614), dim3(256), 0, stream,
                     spa_W_in, Wt_spai, spa_W_out, Wt_spao,
                     spe_W_in, Wt_spei, spe_W_out, Wt_speo);

  // ================= spatial mamba (L=1024, d_model=128) =================
  hipLaunchKernelGGL(ln_rows128_bf16, dim3(8192), dim3(128), 0, stream,
                     x, ln_spa_w, ln_spa_b, Abf);
  hipLaunchKernelGGL(gemm128_split, dim3(6, 64), dim3(256), 0, stream,
                     Abf, Wt_spai, z, xbcraw, dtraw,
                     8192, 644, 128, 256, 640);
  hipLaunchKernelGGL(conv_dtda, dim3(3200), dim3(256), 0, stream,
                     xbcraw, spa_conv_w, spa_conv_b, cv,
                     dtraw, spa_dt_b, spa_A_log, dtb, la,
                     8, 1024, 384, 4, 32768, 3072);
  hipLaunchKernelGGL(ssd_local, dim3(512), dim3(256), 0, stream,
                     cv, dtb, la, xbcraw, dtraw, 16, 4, 384, 256);
  hipLaunchKernelGGL(ssd_carry, dim3(256), dim3(128), 0, stream,
                     xbcraw, dtraw, 16);
  hipLaunchKernelGGL(ssd_out, dim3(512), dim3(256), 0, stream,
                     cv, dtb, la, xbcraw, spa_D, yb, 16, 4, 384, 256);
  hipLaunchKernelGGL((gate_rms_bf16<1>), dim3(8192), dim3(256), 0, stream,
                     yb, z, spa_rms_w, Abf, 256);
  hipLaunchKernelGGL((gemm_mfma<1>), dim3(2, 128), dim3(256), 0, stream,
                     Abf, Wt_spao, x, xspa, 8192, 128, 256);

  // ================= spectral mamba (L=128, d_model=1024) =================
  hipLaunchKernelGGL(spe_stats_part, dim3(4, 8), dim3(256), 0, stream,
                     xspa, dtb);
  hipLaunchKernelGGL(spe_normT, dim3(2, 8, 8), dim3(256), 0, stream,
                     xspa, dtb, ln_spe_w, ln_spe_b, Abf);
  hipLaunchKernelGGL(gemm128_split, dim3(34, 8), dim3(256), 0, stream,
                     Abf, Wt_spei, z, xbcraw, dtraw,
                     1024, 4256, 1024, 2048, 4224);
  hipLaunchKernelGGL(conv_dtda, dim3(2304), dim3(256), 0, stream,
                     xbcraw, spe_conv_w, spe_conv_b, cv,
                     dtraw, spe_dt_b, spe_A_log, dtb, la,
                     8, 128, 2176, 32, 32768, 2176);
  hipLaunchKernelGGL(ssd_local, dim3(512), dim3(256), 0, stream,
                     cv, dtb, la, xbcraw, dtraw, 2, 32, 2176, 2048);
  hipLaunchKernelGGL(ssd_carry, dim3(2048), dim3(128), 0, stream,
                     xbcraw, dtraw, 2);
  hipLaunchKernelGGL(ssd_out, dim3(512), dim3(256), 0, stream,
                     cv, dtb, la, xbcraw, spe_D, yb, 2, 32, 2176, 2048);
  hipLaunchKernelGGL((gate_rms_bf16<8>), dim3(1024), dim3(256), 0, stream,
                     yb, z, spe_rms_w, Abf, 2048);
  hipLaunchKernelGGL((gemm_mfma<2>), dim3(16, 16), dim3(256), 0, stream,
                     Abf, Wt_speo, xspa, out, 1024, 1024, 2048);
}